// Round 1
// baseline (1345.525 us; speedup 1.0000x reference)
//
#include <hip/hip_runtime.h>
#include <math.h>

#define D 128
#define HEADS 4
#define DK 32
#define NUM_HE 20000

// ---------------------------------------------------------------------------
// Stage 1: K = x@Wk + bk, Q = x@Wq + bq  (fused; x staged once in LDS)
// block = 512 threads = 128 cols x 4 row-groups; each thread does 4 rows.
// ---------------------------------------------------------------------------
__global__ void gemm_kq(const float* __restrict__ x,
                        const float* __restrict__ Wk, const float* __restrict__ bk,
                        const float* __restrict__ Wq, const float* __restrict__ bq,
                        float* __restrict__ K, float* __restrict__ Q, int N)
{
    __shared__ float xs[16][D];
    const int c  = threadIdx.x & 127;
    const int rg = threadIdx.x >> 7;       // 0..3
    const int r0 = blockIdx.x * 16;

    for (int i = threadIdx.x; i < 16 * D; i += 512) {
        int rr = i >> 7, cc = i & 127;
        int r = r0 + rr;
        xs[rr][cc] = (r < N) ? x[(size_t)r * D + cc] : 0.f;
    }
    __syncthreads();

    float ak[4] = {0.f, 0.f, 0.f, 0.f};
    float aq[4] = {0.f, 0.f, 0.f, 0.f};
    for (int k = 0; k < D; ++k) {
        float wk = Wk[k * D + c];
        float wq = Wq[k * D + c];
        #pragma unroll
        for (int j = 0; j < 4; ++j) {
            float xv = xs[rg * 4 + j][k];
            ak[j] += xv * wk;
            aq[j] += xv * wq;
        }
    }
    float bkv = bk[c], bqv = bq[c];
    #pragma unroll
    for (int j = 0; j < 4; ++j) {
        int r = r0 + rg * 4 + j;
        if (r < N) {
            K[(size_t)r * D + c] = ak[j] + bkv;
            Q[(size_t)r * D + c] = aq[j] + bqv;
        }
    }
}

// ---------------------------------------------------------------------------
// Stage 2: he_feat_all[he_idx[e]] += K[node_idx[e]]   (atomic scatter-add)
// 128 threads per incidence entry (one per feature dim).
// ---------------------------------------------------------------------------
__global__ void scatter_he(const float* __restrict__ K,
                           const int* __restrict__ node_idx,
                           const int* __restrict__ he_idx,
                           float* __restrict__ he_feat, int E)
{
    int idx = blockIdx.x * blockDim.x + threadIdx.x;
    int e = idx >> 7;
    if (e >= E) return;
    int d = idx & 127;
    int n = node_idx[e];
    int h = he_idx[e];
    atomicAdd(&he_feat[(size_t)h * D + d], K[(size_t)n * D + d]);
}

__global__ void fill_neginf(float* __restrict__ p, int n)
{
    int i = blockIdx.x * blockDim.x + threadIdx.x;
    if (i < n) p[i] = -INFINITY;
}

__device__ __forceinline__ void atomicMaxFloat(float* addr, float val)
{
    if (val >= 0.f) atomicMax((int*)addr, __float_as_int(val));
    else            atomicMin((unsigned int*)addr, __float_as_uint(val));
}

// ---------------------------------------------------------------------------
// Stage 3: alpha[e,h] = dot(Q[node,h,:], he_feat[he,h,:]) / sqrt(DK)
//          + per-(node,head) running max via atomicMax.
// One 64-lane wave per entry; lane loads float2 (dims 2*lane, 2*lane+1);
// lanes [16h,16h+16) cover head h; 16-lane shfl_xor reduce.
// ---------------------------------------------------------------------------
__global__ void alpha_max(const float* __restrict__ Q,
                          const float* __restrict__ he_feat,
                          const int* __restrict__ node_idx,
                          const int* __restrict__ he_idx,
                          float* __restrict__ alpha,
                          float* __restrict__ m, int E)
{
    int e = blockIdx.x * 4 + (threadIdx.x >> 6);
    int lane = threadIdx.x & 63;
    if (e >= E) return;
    int n = node_idx[e];
    int h = he_idx[e];
    float2 q2 = ((const float2*)Q)[(size_t)n * 64 + lane];
    float2 f2 = ((const float2*)he_feat)[(size_t)h * 64 + lane];
    float p = q2.x * f2.x + q2.y * f2.y;
    p += __shfl_xor(p, 1);
    p += __shfl_xor(p, 2);
    p += __shfl_xor(p, 4);
    p += __shfl_xor(p, 8);
    if ((lane & 15) == 0) {
        int head = lane >> 4;
        float a = p * 0.17677669529663687f;  // 1/sqrt(32)
        alpha[(size_t)e * 4 + head] = a;
        atomicMaxFloat(&m[(size_t)n * 4 + head], a);
    }
}

// ---------------------------------------------------------------------------
// Stage 4: ealpha = exp(alpha - m[node]);  s[node,h] += ealpha  (in-place)
// ---------------------------------------------------------------------------
__global__ void exp_sum(float* __restrict__ alpha,
                        const int* __restrict__ node_idx,
                        const float* __restrict__ m,
                        float* __restrict__ s, int E4)
{
    int i = blockIdx.x * blockDim.x + threadIdx.x;
    if (i >= E4) return;
    int e = i >> 2, h = i & 3;
    int n = node_idx[e];
    float ea = __expf(alpha[i] - m[(size_t)n * 4 + h]);
    alpha[i] = ea;
    atomicAdd(&s[(size_t)n * 4 + h], ea);
}

// ---------------------------------------------------------------------------
// Stage 5: node_out[node] += he_feat[he] * (ealpha / (s[node]+1e-16))
// 128 threads per entry.
// ---------------------------------------------------------------------------
__global__ void weighted_scatter(const float* __restrict__ he_feat,
                                 const float* __restrict__ alpha,
                                 const float* __restrict__ s,
                                 const int* __restrict__ node_idx,
                                 const int* __restrict__ he_idx,
                                 float* __restrict__ node_out, int E)
{
    int idx = blockIdx.x * blockDim.x + threadIdx.x;
    int e = idx >> 7;
    if (e >= E) return;
    int d = idx & 127;
    int n = node_idx[e];
    int hh = he_idx[e];
    int head = d >> 5;
    float w = alpha[(size_t)e * 4 + head] / (s[(size_t)n * 4 + head] + 1e-16f);
    atomicAdd(&node_out[(size_t)n * D + d], he_feat[(size_t)hh * D + d] * w);
}

// ---------------------------------------------------------------------------
// Stage 6: out = (node_out + x) @ Wa + ba
// ---------------------------------------------------------------------------
__global__ void gemm_out(const float* __restrict__ no, const float* __restrict__ x,
                         const float* __restrict__ Wa, const float* __restrict__ ba,
                         float* __restrict__ out, int N)
{
    __shared__ float xs[16][D];
    const int c  = threadIdx.x & 127;
    const int rg = threadIdx.x >> 7;
    const int r0 = blockIdx.x * 16;

    for (int i = threadIdx.x; i < 16 * D; i += 512) {
        int rr = i >> 7, cc = i & 127;
        int r = r0 + rr;
        xs[rr][cc] = (r < N) ? (no[(size_t)r * D + cc] + x[(size_t)r * D + cc]) : 0.f;
    }
    __syncthreads();

    float acc[4] = {0.f, 0.f, 0.f, 0.f};
    for (int k = 0; k < D; ++k) {
        float w = Wa[k * D + c];
        #pragma unroll
        for (int j = 0; j < 4; ++j) acc[j] += xs[rg * 4 + j][k] * w;
    }
    float bav = ba[c];
    #pragma unroll
    for (int j = 0; j < 4; ++j) {
        int r = r0 + rg * 4 + j;
        if (r < N) out[(size_t)r * D + c] = acc[j] + bav;
    }
}

// ---------------------------------------------------------------------------
extern "C" void kernel_launch(void* const* d_in, const int* in_sizes, int n_in,
                              void* d_out, int out_size, void* d_ws, size_t ws_size,
                              hipStream_t stream)
{
    const float* x        = (const float*)d_in[0];
    const int*   node_idx = (const int*)d_in[1];
    const int*   he_idx   = (const int*)d_in[2];
    const float* Wk       = (const float*)d_in[3];
    const float* bk       = (const float*)d_in[4];
    const float* Wq       = (const float*)d_in[5];
    const float* bq       = (const float*)d_in[6];
    const float* Wa       = (const float*)d_in[7];
    const float* ba       = (const float*)d_in[8];
    float*       out      = (float*)d_out;

    const int N = in_sizes[0] / D;
    const int E = in_sizes[1];

    // Workspace layout (floats). K buffer is reused as node_out after stage 2.
    float* ws      = (float*)d_ws;
    float* Kbuf    = ws;                               // N*D   (later node_out)
    float* Qbuf    = Kbuf    + (size_t)N * D;          // N*D
    float* he_feat = Qbuf    + (size_t)N * D;          // NUM_HE*D
    float* alpha   = he_feat + (size_t)NUM_HE * D;     // E*4
    float* mbuf    = alpha   + (size_t)E * 4;          // N*4
    float* sbuf    = mbuf    + (size_t)N * 4;          // N*4

    // Stage 1: K, Q projections
    gemm_kq<<<(N + 15) / 16, 512, 0, stream>>>(x, Wk, bk, Wq, bq, Kbuf, Qbuf, N);

    // Stage 2: hyperedge aggregation
    hipMemsetAsync(he_feat, 0, sizeof(float) * (size_t)NUM_HE * D, stream);
    {
        long long tot = (long long)E * D;
        scatter_he<<<(int)((tot + 255) / 256), 256, 0, stream>>>(
            Kbuf, node_idx, he_idx, he_feat, E);
    }

    // Stage 3: attention logits + segment max
    fill_neginf<<<(N * 4 + 255) / 256, 256, 0, stream>>>(mbuf, N * 4);
    alpha_max<<<(E + 3) / 4, 256, 0, stream>>>(Qbuf, he_feat, node_idx, he_idx,
                                               alpha, mbuf, E);

    // Stage 4: exp + segment sum (K no longer needed -> becomes node_out)
    hipMemsetAsync(sbuf, 0, sizeof(float) * (size_t)N * 4, stream);
    hipMemsetAsync(Kbuf, 0, sizeof(float) * (size_t)N * D, stream);
    exp_sum<<<(E * 4 + 255) / 256, 256, 0, stream>>>(alpha, node_idx, mbuf, sbuf, E * 4);

    // Stage 5: weighted scatter to nodes
    {
        long long tot = (long long)E * D;
        weighted_scatter<<<(int)((tot + 255) / 256), 256, 0, stream>>>(
            he_feat, alpha, sbuf, node_idx, he_idx, Kbuf, E);
    }

    // Stage 6: residual + output projection
    gemm_out<<<(N + 15) / 16, 512, 0, stream>>>(Kbuf, x, Wa, ba, out, N);
}

// Round 2
// 850.823 us; speedup vs baseline: 1.5814x; 1.5814x over previous
//
#include <hip/hip_runtime.h>
#include <math.h>

#define D 128
#define HEADS 4
#define DK 32
#define NUM_HE 20000

// ---------------------------------------------------------------------------
// Stage 1: K = x@Wk + bk, Q = x@Wq + bq  (fused; x staged once in LDS)
// ---------------------------------------------------------------------------
__global__ void gemm_kq(const float* __restrict__ x,
                        const float* __restrict__ Wk, const float* __restrict__ bk,
                        const float* __restrict__ Wq, const float* __restrict__ bq,
                        float* __restrict__ K, float* __restrict__ Q, int N)
{
    __shared__ float xs[16][D];
    const int c  = threadIdx.x & 127;
    const int rg = threadIdx.x >> 7;       // 0..3
    const int r0 = blockIdx.x * 16;

    for (int i = threadIdx.x; i < 16 * D; i += 512) {
        int rr = i >> 7, cc = i & 127;
        int r = r0 + rr;
        xs[rr][cc] = (r < N) ? x[(size_t)r * D + cc] : 0.f;
    }
    __syncthreads();

    float ak[4] = {0.f, 0.f, 0.f, 0.f};
    float aq[4] = {0.f, 0.f, 0.f, 0.f};
    for (int k = 0; k < D; ++k) {
        float wk = Wk[k * D + c];
        float wq = Wq[k * D + c];
        #pragma unroll
        for (int j = 0; j < 4; ++j) {
            float xv = xs[rg * 4 + j][k];
            ak[j] += xv * wk;
            aq[j] += xv * wq;
        }
    }
    float bkv = bk[c], bqv = bq[c];
    #pragma unroll
    for (int j = 0; j < 4; ++j) {
        int r = r0 + rg * 4 + j;
        if (r < N) {
            K[(size_t)r * D + c] = ak[j] + bkv;
            Q[(size_t)r * D + c] = aq[j] + bqv;
        }
    }
}

// ---------------------------------------------------------------------------
// CSR construction: histogram -> single-block exclusive scan -> fill
// ---------------------------------------------------------------------------
__global__ void hist_kernel(const int* __restrict__ seg, int* __restrict__ cnt, int E)
{
    int e = blockIdx.x * blockDim.x + threadIdx.x;
    if (e < E) atomicAdd(&cnt[seg[e]], 1);
}

// single block, 1024 threads; ptr gets exclusive scan (+ total at ptr[n]),
// cursor gets a copy of the exclusive scan.
__global__ void exclusive_scan(const int* __restrict__ cnt,
                               int* __restrict__ ptr,
                               int* __restrict__ cursor, int n)
{
    __shared__ int wsum[16];
    __shared__ int carry_s;
    const int tid  = threadIdx.x;
    const int lane = tid & 63;
    const int wid  = tid >> 6;
    if (tid == 0) carry_s = 0;
    __syncthreads();
    const int nloop = (n + 1023) / 1024;
    for (int c = 0; c < nloop; ++c) {
        int i = c * 1024 + tid;
        int v = (i < n) ? cnt[i] : 0;
        // inclusive scan within wave
        int x = v;
        #pragma unroll
        for (int off = 1; off < 64; off <<= 1) {
            int y = __shfl_up(x, off);
            if (lane >= off) x += y;
        }
        if (lane == 63) wsum[wid] = x;
        __syncthreads();
        if (wid == 0) {
            int wv = (lane < 16) ? wsum[lane] : 0;
            #pragma unroll
            for (int off = 1; off < 16; off <<= 1) {
                int y = __shfl_up(wv, off);
                if (lane >= off) wv += y;
            }
            if (lane < 16) wsum[lane] = wv;
        }
        __syncthreads();
        int carry = carry_s;
        int base = carry + (wid > 0 ? wsum[wid - 1] : 0);
        int excl = base + x - v;
        if (i < n) { ptr[i] = excl; cursor[i] = excl; }
        __syncthreads();
        if (tid == 0) carry_s = carry + wsum[15];
        __syncthreads();
    }
    if (tid == 0) ptr[n] = carry_s;
}

// out[pos] = val[e] for entries grouped by seg[e]
__global__ void csr_fill(const int* __restrict__ seg, const int* __restrict__ val,
                         int* __restrict__ cursor, int* __restrict__ out, int E)
{
    int e = blockIdx.x * blockDim.x + threadIdx.x;
    if (e >= E) return;
    int pos = atomicAdd(&cursor[seg[e]], 1);
    out[pos] = val[e];
}

// ---------------------------------------------------------------------------
// Stage 2: he_feat[h] = sum of K rows of member nodes (gather, one wave/he)
// ---------------------------------------------------------------------------
__global__ void gather_he(const float* __restrict__ K,
                          const int* __restrict__ he_ptr,
                          const int* __restrict__ members,
                          float* __restrict__ he_feat, int HE)
{
    int h = blockIdx.x * 4 + (threadIdx.x >> 6);
    int lane = threadIdx.x & 63;
    if (h >= HE) return;
    int beg = he_ptr[h], end = he_ptr[h + 1];
    float ax = 0.f, ay = 0.f;
    for (int p = beg; p < end; ++p) {
        int n = members[p];
        float2 k2 = ((const float2*)K)[(size_t)n * 64 + lane];
        ax += k2.x; ay += k2.y;
    }
    ((float2*)he_feat)[(size_t)h * 64 + lane] = make_float2(ax, ay);
}

// ---------------------------------------------------------------------------
// Stages 3-5 fused: per node, online softmax over incident hyperedges and
// weighted accumulation. One wave per node; lane holds dims (2l, 2l+1);
// lanes [16h,16h+16) = head h; 16-lane shfl_xor dot reduction.
// ---------------------------------------------------------------------------
__global__ void fused_attn(const float* __restrict__ Q,
                           const float* __restrict__ he_feat,
                           const int* __restrict__ node_ptr,
                           const int* __restrict__ hes,
                           float* __restrict__ node_out, int N)
{
    int n = blockIdx.x * 4 + (threadIdx.x >> 6);
    int lane = threadIdx.x & 63;
    if (n >= N) return;
    int beg = node_ptr[n], end = node_ptr[n + 1];
    float2 q2 = ((const float2*)Q)[(size_t)n * 64 + lane];
    float m = -INFINITY, s = 0.f;
    float ax = 0.f, ay = 0.f;
    for (int p = beg; p < end; ++p) {
        int h = hes[p];
        float2 f2 = ((const float2*)he_feat)[(size_t)h * 64 + lane];
        float d = q2.x * f2.x + q2.y * f2.y;
        d += __shfl_xor(d, 1);
        d += __shfl_xor(d, 2);
        d += __shfl_xor(d, 4);
        d += __shfl_xor(d, 8);
        float a = d * 0.17677669529663687f;      // 1/sqrt(32)
        float newm = fmaxf(m, a);
        float scale = __expf(m - newm);          // 0 when m=-inf
        float w = __expf(a - newm);
        s = s * scale + w;
        ax = ax * scale + w * f2.x;
        ay = ay * scale + w * f2.y;
        m = newm;
    }
    float inv = 1.f / (s + 1e-16f);
    ((float2*)node_out)[(size_t)n * 64 + lane] = make_float2(ax * inv, ay * inv);
}

// ---------------------------------------------------------------------------
// Stage 6: out = (node_out + x) @ Wa + ba
// ---------------------------------------------------------------------------
__global__ void gemm_out(const float* __restrict__ no, const float* __restrict__ x,
                         const float* __restrict__ Wa, const float* __restrict__ ba,
                         float* __restrict__ out, int N)
{
    __shared__ float xs[16][D];
    const int c  = threadIdx.x & 127;
    const int rg = threadIdx.x >> 7;
    const int r0 = blockIdx.x * 16;

    for (int i = threadIdx.x; i < 16 * D; i += 512) {
        int rr = i >> 7, cc = i & 127;
        int r = r0 + rr;
        xs[rr][cc] = (r < N) ? (no[(size_t)r * D + cc] + x[(size_t)r * D + cc]) : 0.f;
    }
    __syncthreads();

    float acc[4] = {0.f, 0.f, 0.f, 0.f};
    for (int k = 0; k < D; ++k) {
        float w = Wa[k * D + c];
        #pragma unroll
        for (int j = 0; j < 4; ++j) acc[j] += xs[rg * 4 + j][k] * w;
    }
    float bav = ba[c];
    #pragma unroll
    for (int j = 0; j < 4; ++j) {
        int r = r0 + rg * 4 + j;
        if (r < N) out[(size_t)r * D + c] = acc[j] + bav;
    }
}

// ---------------------------------------------------------------------------
extern "C" void kernel_launch(void* const* d_in, const int* in_sizes, int n_in,
                              void* d_out, int out_size, void* d_ws, size_t ws_size,
                              hipStream_t stream)
{
    const float* x        = (const float*)d_in[0];
    const int*   node_idx = (const int*)d_in[1];
    const int*   he_idx   = (const int*)d_in[2];
    const float* Wk       = (const float*)d_in[3];
    const float* bk       = (const float*)d_in[4];
    const float* Wq       = (const float*)d_in[5];
    const float* bq       = (const float*)d_in[6];
    const float* Wa       = (const float*)d_in[7];
    const float* ba       = (const float*)d_in[8];
    float*       out      = (float*)d_out;

    const int N = in_sizes[0] / D;
    const int E = in_sizes[1];

    // Workspace layout. Kbuf is reused as node_out after gather_he consumes K.
    float* ws      = (float*)d_ws;
    float* Kbuf    = ws;                               // N*D  (later node_out)
    float* Qbuf    = Kbuf    + (size_t)N * D;          // N*D
    float* he_feat = Qbuf    + (size_t)N * D;          // NUM_HE*D
    int*   ibase   = (int*)(he_feat + (size_t)NUM_HE * D);
    int*   he_ptr  = ibase;                            // NUM_HE+1
    int*   he_cur  = he_ptr  + (NUM_HE + 1);           // NUM_HE
    int*   he_mem  = he_cur  + NUM_HE;                 // E (node ids by he)
    int*   nd_ptr  = he_mem  + E;                      // N+1
    int*   nd_cur  = nd_ptr  + (N + 1);                // N
    int*   nd_he   = nd_cur  + N;                      // E (he ids by node)

    // Stage 1: K, Q projections
    gemm_kq<<<(N + 15) / 16, 512, 0, stream>>>(x, Wk, bk, Wq, bq, Kbuf, Qbuf, N);

    // CSR by hyperedge (histogram reuses he_cur as counter buffer)
    hipMemsetAsync(he_cur, 0, sizeof(int) * NUM_HE, stream);
    hist_kernel<<<(E + 255) / 256, 256, 0, stream>>>(he_idx, he_cur, E);
    exclusive_scan<<<1, 1024, 0, stream>>>(he_cur, he_ptr, he_cur, NUM_HE);
    csr_fill<<<(E + 255) / 256, 256, 0, stream>>>(he_idx, node_idx, he_cur, he_mem, E);

    // CSR by node
    hipMemsetAsync(nd_cur, 0, sizeof(int) * N, stream);
    hist_kernel<<<(E + 255) / 256, 256, 0, stream>>>(node_idx, nd_cur, E);
    exclusive_scan<<<1, 1024, 0, stream>>>(nd_cur, nd_ptr, nd_cur, N);
    csr_fill<<<(E + 255) / 256, 256, 0, stream>>>(node_idx, he_idx, nd_cur, nd_he, E);

    // Stage 2: hyperedge aggregation (gather)
    gather_he<<<(NUM_HE + 3) / 4, 256, 0, stream>>>(Kbuf, he_ptr, he_mem, he_feat, NUM_HE);

    // Stages 3-5: fused attention (K consumed; Kbuf becomes node_out)
    fused_attn<<<(N + 3) / 4, 256, 0, stream>>>(Qbuf, he_feat, nd_ptr, nd_he, Kbuf, N);

    // Stage 6: residual + output projection
    gemm_out<<<(N + 15) / 16, 512, 0, stream>>>(Kbuf, x, Wa, ba, out, N);
}

// Round 3
// 718.704 us; speedup vs baseline: 1.8722x; 1.1838x over previous
//
#include <hip/hip_runtime.h>
#include <math.h>

#define D 128
#define HEADS 4
#define DK 32
#define NUM_HE 20000

typedef short bf16x8 __attribute__((ext_vector_type(8)));
typedef float f32x4  __attribute__((ext_vector_type(4)));

__device__ __forceinline__ unsigned short f2bf(float f) {
    unsigned int u = __float_as_uint(f);
    u = (u + 0x7fffu + ((u >> 16) & 1u)) >> 16;
    return (unsigned short)u;
}
__device__ __forceinline__ float bf2f(unsigned short h) {
    return __uint_as_float(((unsigned int)h) << 16);
}

// ---------------------------------------------------------------------------
// W preprocessing: fragment-order Wk|Wq|Wa as bf16 hi/lo.
// dst layout per W: [hi:16384][lo:16384] ushorts, fragment index
// ((ks*8+nf)*64+lane)*8+j  <->  W[ks*32+(lane>>4)*8+j][nf*16+(lane&15)]
// ---------------------------------------------------------------------------
__global__ void wprep(const float* __restrict__ Wk, const float* __restrict__ Wq,
                      const float* __restrict__ Wa, unsigned short* __restrict__ dst)
{
    int t = blockIdx.x * blockDim.x + threadIdx.x;
    if (t >= 3 * 16384) return;
    int w = t >> 14, rem = t & 16383;
    int ks = rem >> 12, nf = (rem >> 9) & 7, lane = (rem >> 3) & 63, j = rem & 7;
    int r = ks * 32 + (lane >> 4) * 8 + j;
    int c = nf * 16 + (lane & 15);
    const float* W = (w == 0) ? Wk : (w == 1) ? Wq : Wa;
    float v = W[r * 128 + c];
    unsigned short h = f2bf(v);
    dst[(size_t)w * 32768 + rem]         = h;
    dst[(size_t)w * 32768 + 16384 + rem] = f2bf(v - bf2f(h));
}

// ---------------------------------------------------------------------------
// Split-bf16 MFMA GEMM: C[M,128] = (A (+R)) @ W + bias, W pre-fragmented.
// Block = 4 waves; wave owns 32 rows x 128 cols (2 M-frag x 8 N-frag).
// acc += Ahi*Whi + Ahi*Wlo + Alo*Whi   (~fp32 accuracy)
// ---------------------------------------------------------------------------
template<bool RES>
__global__ __launch_bounds__(256) void gemm_split(
    const float* __restrict__ A, const float* __restrict__ R,
    const unsigned short* __restrict__ Bh, const unsigned short* __restrict__ Bl,
    const float* __restrict__ bias, float* __restrict__ C, int M)
{
    const int lane = threadIdx.x & 63;
    const int wv   = threadIdx.x >> 6;
    const int r0   = blockIdx.x * 128 + wv * 32;
    const int lr   = lane & 15;
    const int kg   = lane >> 4;

    f32x4 acc[2][8];
    #pragma unroll
    for (int m = 0; m < 2; ++m)
        #pragma unroll
        for (int n = 0; n < 8; ++n) acc[m][n] = (f32x4){0.f, 0.f, 0.f, 0.f};

    int row[2];
    row[0] = min(r0 + lr,      M - 1);
    row[1] = min(r0 + 16 + lr, M - 1);

    for (int ks = 0; ks < 4; ++ks) {
        bf16x8 ah[2], al[2];
        #pragma unroll
        for (int m = 0; m < 2; ++m) {
            const float* p = A + (size_t)row[m] * D + ks * 32 + kg * 8;
            float4 v0 = *(const float4*)p;
            float4 v1 = *(const float4*)(p + 4);
            float vv[8] = {v0.x, v0.y, v0.z, v0.w, v1.x, v1.y, v1.z, v1.w};
            if (RES) {
                const float* q = R + (size_t)row[m] * D + ks * 32 + kg * 8;
                float4 u0 = *(const float4*)q;
                float4 u1 = *(const float4*)(q + 4);
                vv[0] += u0.x; vv[1] += u0.y; vv[2] += u0.z; vv[3] += u0.w;
                vv[4] += u1.x; vv[5] += u1.y; vv[6] += u1.z; vv[7] += u1.w;
            }
            #pragma unroll
            for (int j = 0; j < 8; ++j) {
                unsigned short h = f2bf(vv[j]);
                ah[m][j] = (short)h;
                al[m][j] = (short)f2bf(vv[j] - bf2f(h));
            }
        }
        #pragma unroll
        for (int nf = 0; nf < 8; ++nf) {
            const int boff = ((ks * 8 + nf) * 64 + lane) * 8;
            bf16x8 bh = *(const bf16x8*)(const void*)(Bh + boff);
            bf16x8 bl = *(const bf16x8*)(const void*)(Bl + boff);
            #pragma unroll
            for (int m = 0; m < 2; ++m) {
                acc[m][nf] = __builtin_amdgcn_mfma_f32_16x16x32_bf16(ah[m], bh, acc[m][nf], 0, 0, 0);
                acc[m][nf] = __builtin_amdgcn_mfma_f32_16x16x32_bf16(ah[m], bl, acc[m][nf], 0, 0, 0);
                acc[m][nf] = __builtin_amdgcn_mfma_f32_16x16x32_bf16(al[m], bh, acc[m][nf], 0, 0, 0);
            }
        }
    }

    #pragma unroll
    for (int nf = 0; nf < 8; ++nf) {
        int col = nf * 16 + lr;
        float bv = bias[col];
        #pragma unroll
        for (int m = 0; m < 2; ++m) {
            #pragma unroll
            for (int j = 0; j < 4; ++j) {
                int gr = r0 + m * 16 + kg * 4 + j;
                if (gr < M) C[(size_t)gr * D + col] = acc[m][nf][j] + bv;
            }
        }
    }
}

// ---------------------------------------------------------------------------
// CSR construction: histogram -> single-block exclusive scan -> fill
// ---------------------------------------------------------------------------
__global__ void hist_kernel(const int* __restrict__ seg, int* __restrict__ cnt, int E)
{
    int e = blockIdx.x * blockDim.x + threadIdx.x;
    if (e < E) atomicAdd(&cnt[seg[e]], 1);
}

__global__ void exclusive_scan(const int* __restrict__ cnt,
                               int* __restrict__ ptr,
                               int* __restrict__ cursor, int n)
{
    __shared__ int wsum[16];
    __shared__ int carry_s;
    const int tid  = threadIdx.x;
    const int lane = tid & 63;
    const int wid  = tid >> 6;
    if (tid == 0) carry_s = 0;
    __syncthreads();
    const int nloop = (n + 1023) / 1024;
    for (int c = 0; c < nloop; ++c) {
        int i = c * 1024 + tid;
        int v = (i < n) ? cnt[i] : 0;
        int x = v;
        #pragma unroll
        for (int off = 1; off < 64; off <<= 1) {
            int y = __shfl_up(x, off);
            if (lane >= off) x += y;
        }
        if (lane == 63) wsum[wid] = x;
        __syncthreads();
        if (wid == 0) {
            int wv = (lane < 16) ? wsum[lane] : 0;
            #pragma unroll
            for (int off = 1; off < 16; off <<= 1) {
                int y = __shfl_up(wv, off);
                if (lane >= off) wv += y;
            }
            if (lane < 16) wsum[lane] = wv;
        }
        __syncthreads();
        int carry = carry_s;
        int base = carry + (wid > 0 ? wsum[wid - 1] : 0);
        int excl = base + x - v;
        if (i < n) { ptr[i] = excl; cursor[i] = excl; }
        __syncthreads();
        if (tid == 0) carry_s = carry + wsum[15];
        __syncthreads();
    }
    if (tid == 0) ptr[n] = carry_s;
}

__global__ void csr_fill(const int* __restrict__ seg, const int* __restrict__ val,
                         int* __restrict__ cursor, int* __restrict__ out, int E)
{
    int e = blockIdx.x * blockDim.x + threadIdx.x;
    if (e >= E) return;
    int pos = atomicAdd(&cursor[seg[e]], 1);
    out[pos] = val[e];
}

// ---------------------------------------------------------------------------
// Stage 2: he_feat[h] = sum of K rows of member nodes (gather, one wave/he)
// ---------------------------------------------------------------------------
__global__ void gather_he(const float* __restrict__ K,
                          const int* __restrict__ he_ptr,
                          const int* __restrict__ members,
                          float* __restrict__ he_feat, int HE)
{
    int h = blockIdx.x * 4 + (threadIdx.x >> 6);
    int lane = threadIdx.x & 63;
    if (h >= HE) return;
    int beg = he_ptr[h], end = he_ptr[h + 1];
    float ax = 0.f, ay = 0.f;
    for (int p = beg; p < end; ++p) {
        int n = members[p];
        float2 k2 = ((const float2*)K)[(size_t)n * 64 + lane];
        ax += k2.x; ay += k2.y;
    }
    ((float2*)he_feat)[(size_t)h * 64 + lane] = make_float2(ax, ay);
}

// ---------------------------------------------------------------------------
// Stages 3-5 fused: per-node online softmax + weighted accumulate.
// ---------------------------------------------------------------------------
__global__ void fused_attn(const float* __restrict__ Q,
                           const float* __restrict__ he_feat,
                           const int* __restrict__ node_ptr,
                           const int* __restrict__ hes,
                           float* __restrict__ node_out, int N)
{
    int n = blockIdx.x * 4 + (threadIdx.x >> 6);
    int lane = threadIdx.x & 63;
    if (n >= N) return;
    int beg = node_ptr[n], end = node_ptr[n + 1];
    float2 q2 = ((const float2*)Q)[(size_t)n * 64 + lane];
    float m = -INFINITY, s = 0.f;
    float ax = 0.f, ay = 0.f;
    for (int p = beg; p < end; ++p) {
        int h = hes[p];
        float2 f2 = ((const float2*)he_feat)[(size_t)h * 64 + lane];
        float d = q2.x * f2.x + q2.y * f2.y;
        d += __shfl_xor(d, 1);
        d += __shfl_xor(d, 2);
        d += __shfl_xor(d, 4);
        d += __shfl_xor(d, 8);
        float a = d * 0.17677669529663687f;      // 1/sqrt(32)
        float newm = fmaxf(m, a);
        float scale = __expf(m - newm);          // 0 when m=-inf
        float w = __expf(a - newm);
        s = s * scale + w;
        ax = ax * scale + w * f2.x;
        ay = ay * scale + w * f2.y;
        m = newm;
    }
    float inv = 1.f / (s + 1e-16f);
    ((float2*)node_out)[(size_t)n * 64 + lane] = make_float2(ax * inv, ay * inv);
}

// ---------------------------------------------------------------------------
extern "C" void kernel_launch(void* const* d_in, const int* in_sizes, int n_in,
                              void* d_out, int out_size, void* d_ws, size_t ws_size,
                              hipStream_t stream)
{
    const float* x        = (const float*)d_in[0];
    const int*   node_idx = (const int*)d_in[1];
    const int*   he_idx   = (const int*)d_in[2];
    const float* Wk       = (const float*)d_in[3];
    const float* bk       = (const float*)d_in[4];
    const float* Wq       = (const float*)d_in[5];
    const float* bq       = (const float*)d_in[6];
    const float* Wa       = (const float*)d_in[7];
    const float* ba       = (const float*)d_in[8];
    float*       out      = (float*)d_out;

    const int N = in_sizes[0] / D;
    const int E = in_sizes[1];

    // Workspace layout. Kbuf reused as node_out after gather_he consumes K.
    float* ws      = (float*)d_ws;
    float* Kbuf    = ws;                               // N*D  (later node_out)
    float* Qbuf    = Kbuf    + (size_t)N * D;          // N*D
    float* he_feat = Qbuf    + (size_t)N * D;          // NUM_HE*D
    unsigned short* wfrag = (unsigned short*)(he_feat + (size_t)NUM_HE * D); // 3*32768
    int*   ibase   = (int*)(wfrag + 3 * 32768);
    int*   he_ptr  = ibase;                            // NUM_HE+1
    int*   he_cur  = he_ptr  + (NUM_HE + 1);           // NUM_HE
    int*   he_mem  = he_cur  + NUM_HE;                 // E (node ids by he)
    int*   nd_ptr  = he_mem  + E;                      // N+1
    int*   nd_cur  = nd_ptr  + (N + 1);                // N
    int*   nd_he   = nd_cur  + N;                      // E (he ids by node)

    const int gemm_grid = (N + 127) / 128;

    // W fragments (hi/lo) for all three projections
    wprep<<<(3 * 16384 + 255) / 256, 256, 0, stream>>>(Wk, Wq, Wa, wfrag);

    // Stage 1: K, Q projections (split-bf16 MFMA)
    gemm_split<false><<<gemm_grid, 256, 0, stream>>>(
        x, nullptr, wfrag, wfrag + 16384, bk, Kbuf, N);
    gemm_split<false><<<gemm_grid, 256, 0, stream>>>(
        x, nullptr, wfrag + 32768, wfrag + 49152, bq, Qbuf, N);

    // CSR by hyperedge
    hipMemsetAsync(he_cur, 0, sizeof(int) * NUM_HE, stream);
    hist_kernel<<<(E + 255) / 256, 256, 0, stream>>>(he_idx, he_cur, E);
    exclusive_scan<<<1, 1024, 0, stream>>>(he_cur, he_ptr, he_cur, NUM_HE);
    csr_fill<<<(E + 255) / 256, 256, 0, stream>>>(he_idx, node_idx, he_cur, he_mem, E);

    // CSR by node
    hipMemsetAsync(nd_cur, 0, sizeof(int) * N, stream);
    hist_kernel<<<(E + 255) / 256, 256, 0, stream>>>(node_idx, nd_cur, E);
    exclusive_scan<<<1, 1024, 0, stream>>>(nd_cur, nd_ptr, nd_cur, N);
    csr_fill<<<(E + 255) / 256, 256, 0, stream>>>(node_idx, he_idx, nd_cur, nd_he, E);

    // Stage 2: hyperedge aggregation (gather)
    gather_he<<<(NUM_HE + 3) / 4, 256, 0, stream>>>(Kbuf, he_ptr, he_mem, he_feat, NUM_HE);

    // Stages 3-5: fused attention (K consumed; Kbuf becomes node_out)
    fused_attn<<<(N + 3) / 4, 256, 0, stream>>>(Qbuf, he_feat, nd_ptr, nd_he, Kbuf, N);

    // Stage 6: residual folded into A-load; split-bf16 MFMA
    gemm_split<true><<<gemm_grid, 256, 0, stream>>>(
        Kbuf, x, wfrag + 65536, wfrag + 81920, ba, out, N);
}

// Round 4
// 532.522 us; speedup vs baseline: 2.5267x; 1.3496x over previous
//
#include <hip/hip_runtime.h>
#include <math.h>

#define D 128
#define HEADS 4
#define DK 32
#define NUM_HE 20000

typedef short bf16x8 __attribute__((ext_vector_type(8)));
typedef float f32x4  __attribute__((ext_vector_type(4)));

__device__ __forceinline__ unsigned short f2bf(float f) {
    unsigned int u = __float_as_uint(f);
    u = (u + 0x7fffu + ((u >> 16) & 1u)) >> 16;
    return (unsigned short)u;
}
__device__ __forceinline__ float bf2f(unsigned short h) {
    return __uint_as_float(((unsigned int)h) << 16);
}

// ---------------------------------------------------------------------------
// W preprocessing: fragment-order Wk|Wq|Wa as bf16 hi/lo.
// ---------------------------------------------------------------------------
__global__ void wprep(const float* __restrict__ Wk, const float* __restrict__ Wq,
                      const float* __restrict__ Wa, unsigned short* __restrict__ dst)
{
    int t = blockIdx.x * blockDim.x + threadIdx.x;
    if (t >= 3 * 16384) return;
    int w = t >> 14, rem = t & 16383;
    int ks = rem >> 12, nf = (rem >> 9) & 7, lane = (rem >> 3) & 63, j = rem & 7;
    int r = ks * 32 + (lane >> 4) * 8 + j;
    int c = nf * 16 + (lane & 15);
    const float* W = (w == 0) ? Wk : (w == 1) ? Wq : Wa;
    float v = W[r * 128 + c];
    unsigned short h = f2bf(v);
    dst[(size_t)w * 32768 + rem]         = h;
    dst[(size_t)w * 32768 + 16384 + rem] = f2bf(v - bf2f(h));
}

// ---------------------------------------------------------------------------
// Split-bf16 MFMA GEMM: C[M,128] = (A (+R)) @ W + bias, W pre-fragmented.
// ---------------------------------------------------------------------------
template<bool RES>
__global__ __launch_bounds__(256) void gemm_split(
    const float* __restrict__ A, const float* __restrict__ R,
    const unsigned short* __restrict__ Bh, const unsigned short* __restrict__ Bl,
    const float* __restrict__ bias, float* __restrict__ C, int M)
{
    const int lane = threadIdx.x & 63;
    const int wv   = threadIdx.x >> 6;
    const int r0   = blockIdx.x * 128 + wv * 32;
    const int lr   = lane & 15;
    const int kg   = lane >> 4;

    f32x4 acc[2][8];
    #pragma unroll
    for (int m = 0; m < 2; ++m)
        #pragma unroll
        for (int n = 0; n < 8; ++n) acc[m][n] = (f32x4){0.f, 0.f, 0.f, 0.f};

    int row[2];
    row[0] = min(r0 + lr,      M - 1);
    row[1] = min(r0 + 16 + lr, M - 1);

    for (int ks = 0; ks < 4; ++ks) {
        bf16x8 ah[2], al[2];
        #pragma unroll
        for (int m = 0; m < 2; ++m) {
            const float* p = A + (size_t)row[m] * D + ks * 32 + kg * 8;
            float4 v0 = *(const float4*)p;
            float4 v1 = *(const float4*)(p + 4);
            float vv[8] = {v0.x, v0.y, v0.z, v0.w, v1.x, v1.y, v1.z, v1.w};
            if (RES) {
                const float* q = R + (size_t)row[m] * D + ks * 32 + kg * 8;
                float4 u0 = *(const float4*)q;
                float4 u1 = *(const float4*)(q + 4);
                vv[0] += u0.x; vv[1] += u0.y; vv[2] += u0.z; vv[3] += u0.w;
                vv[4] += u1.x; vv[5] += u1.y; vv[6] += u1.z; vv[7] += u1.w;
            }
            #pragma unroll
            for (int j = 0; j < 8; ++j) {
                unsigned short h = f2bf(vv[j]);
                ah[m][j] = (short)h;
                al[m][j] = (short)f2bf(vv[j] - bf2f(h));
            }
        }
        #pragma unroll
        for (int nf = 0; nf < 8; ++nf) {
            const int boff = ((ks * 8 + nf) * 64 + lane) * 8;
            bf16x8 bh = *(const bf16x8*)(const void*)(Bh + boff);
            bf16x8 bl = *(const bf16x8*)(const void*)(Bl + boff);
            #pragma unroll
            for (int m = 0; m < 2; ++m) {
                acc[m][nf] = __builtin_amdgcn_mfma_f32_16x16x32_bf16(ah[m], bh, acc[m][nf], 0, 0, 0);
                acc[m][nf] = __builtin_amdgcn_mfma_f32_16x16x32_bf16(ah[m], bl, acc[m][nf], 0, 0, 0);
                acc[m][nf] = __builtin_amdgcn_mfma_f32_16x16x32_bf16(al[m], bh, acc[m][nf], 0, 0, 0);
            }
        }
    }

    #pragma unroll
    for (int nf = 0; nf < 8; ++nf) {
        int col = nf * 16 + lr;
        float bv = bias[col];
        #pragma unroll
        for (int m = 0; m < 2; ++m) {
            #pragma unroll
            for (int j = 0; j < 4; ++j) {
                int gr = r0 + m * 16 + kg * 4 + j;
                if (gr < M) C[(size_t)gr * D + col] = acc[m][nf][j] + bv;
            }
        }
    }
}

// ---------------------------------------------------------------------------
// CSR construction: histogram -> 3-phase multi-block exclusive scan -> fill
// ---------------------------------------------------------------------------
__global__ void hist_kernel(const int* __restrict__ seg, int* __restrict__ cnt, int E)
{
    int e = blockIdx.x * blockDim.x + threadIdx.x;
    if (e < E) atomicAdd(&cnt[seg[e]], 1);
}

// Phase A: per-block (1024 elems) exclusive scan + block totals.
__global__ void scan_block(const int* __restrict__ cnt, int* __restrict__ excl,
                           int* __restrict__ partials, int n)
{
    __shared__ int wsum[16];
    const int tid  = threadIdx.x;
    const int lane = tid & 63;
    const int wid  = tid >> 6;
    int i = blockIdx.x * 1024 + tid;
    int v = (i < n) ? cnt[i] : 0;
    int x = v;
    #pragma unroll
    for (int off = 1; off < 64; off <<= 1) {
        int y = __shfl_up(x, off);
        if (lane >= off) x += y;
    }
    if (lane == 63) wsum[wid] = x;
    __syncthreads();
    if (wid == 0) {
        int wv = (lane < 16) ? wsum[lane] : 0;
        #pragma unroll
        for (int off = 1; off < 16; off <<= 1) {
            int y = __shfl_up(wv, off);
            if (lane >= off) wv += y;
        }
        if (lane < 16) wsum[lane] = wv;
    }
    __syncthreads();
    int base = (wid > 0) ? wsum[wid - 1] : 0;
    if (i < n) excl[i] = base + x - v;
    if (tid == 1023) partials[blockIdx.x] = base + x;   // block total
}

// Phase B: exclusive-scan the block partials (np <= 128); total -> *total.
__global__ void scan_partials(int* __restrict__ partials, int* __restrict__ total, int np)
{
    __shared__ int ws[2];
    const int tid = threadIdx.x, lane = tid & 63, wid = tid >> 6;
    int v = (tid < np) ? partials[tid] : 0;
    int x = v;
    #pragma unroll
    for (int off = 1; off < 64; off <<= 1) {
        int y = __shfl_up(x, off);
        if (lane >= off) x += y;
    }
    if (lane == 63) ws[wid] = x;
    __syncthreads();
    int incl = x + ((wid == 1) ? ws[0] : 0);
    if (tid < np) partials[tid] = incl - v;             // exclusive
    if (tid == np - 1) *total = incl;                   // grand total
}

// Phase C: add scanned partials; write ptr and cursor copy.
__global__ void scan_add(int* __restrict__ ptr, int* __restrict__ cursor,
                         const int* __restrict__ partials, int n)
{
    int i = blockIdx.x * blockDim.x + threadIdx.x;
    if (i >= n) return;
    int v = ptr[i] + partials[i >> 10];
    ptr[i] = v;
    cursor[i] = v;
}

__global__ void csr_fill(const int* __restrict__ seg, const int* __restrict__ val,
                         int* __restrict__ cursor, int* __restrict__ out, int E)
{
    int e = blockIdx.x * blockDim.x + threadIdx.x;
    if (e >= E) return;
    int pos = atomicAdd(&cursor[seg[e]], 1);
    out[pos] = val[e];
}

// ---------------------------------------------------------------------------
// Stage 2: he_feat[h] = sum of member K rows (gather, one wave/he, 4x ILP)
// ---------------------------------------------------------------------------
__global__ void gather_he(const float* __restrict__ K,
                          const int* __restrict__ he_ptr,
                          const int* __restrict__ members,
                          float* __restrict__ he_feat, int HE)
{
    int h = blockIdx.x * 4 + (threadIdx.x >> 6);
    int lane = threadIdx.x & 63;
    if (h >= HE) return;
    int beg = he_ptr[h], end = he_ptr[h + 1];
    float ax = 0.f, ay = 0.f;
    int p = beg;
    for (; p + 3 < end; p += 4) {
        int n0 = members[p],     n1 = members[p + 1];
        int n2 = members[p + 2], n3 = members[p + 3];
        float2 k0 = ((const float2*)K)[(size_t)n0 * 64 + lane];
        float2 k1 = ((const float2*)K)[(size_t)n1 * 64 + lane];
        float2 k2 = ((const float2*)K)[(size_t)n2 * 64 + lane];
        float2 k3 = ((const float2*)K)[(size_t)n3 * 64 + lane];
        ax += (k0.x + k1.x) + (k2.x + k3.x);
        ay += (k0.y + k1.y) + (k2.y + k3.y);
    }
    for (; p < end; ++p) {
        int n = members[p];
        float2 k2v = ((const float2*)K)[(size_t)n * 64 + lane];
        ax += k2v.x; ay += k2v.y;
    }
    ((float2*)he_feat)[(size_t)h * 64 + lane] = make_float2(ax, ay);
}

// ---------------------------------------------------------------------------
// Stages 3-5 fused: per-node online softmax + weighted accumulate, 4x ILP.
// ---------------------------------------------------------------------------
__global__ void fused_attn(const float* __restrict__ Q,
                           const float* __restrict__ he_feat,
                           const int* __restrict__ node_ptr,
                           const int* __restrict__ hes,
                           float* __restrict__ node_out, int N)
{
    const float SC = 0.17677669529663687f;   // 1/sqrt(32)
    int n = blockIdx.x * 4 + (threadIdx.x >> 6);
    int lane = threadIdx.x & 63;
    if (n >= N) return;
    int beg = node_ptr[n], end = node_ptr[n + 1];
    float2 q2 = ((const float2*)Q)[(size_t)n * 64 + lane];
    float m = -INFINITY, s = 0.f, ax = 0.f, ay = 0.f;

    int p = beg;
    for (; p + 3 < end; p += 4) {
        int h0 = hes[p],     h1 = hes[p + 1];
        int h2 = hes[p + 2], h3 = hes[p + 3];
        float2 f0 = ((const float2*)he_feat)[(size_t)h0 * 64 + lane];
        float2 f1 = ((const float2*)he_feat)[(size_t)h1 * 64 + lane];
        float2 f2 = ((const float2*)he_feat)[(size_t)h2 * 64 + lane];
        float2 f3 = ((const float2*)he_feat)[(size_t)h3 * 64 + lane];
        float d0 = q2.x * f0.x + q2.y * f0.y;
        float d1 = q2.x * f1.x + q2.y * f1.y;
        float d2 = q2.x * f2.x + q2.y * f2.y;
        float d3 = q2.x * f3.x + q2.y * f3.y;
        #pragma unroll
        for (int off = 1; off <= 8; off <<= 1) {
            d0 += __shfl_xor(d0, off);
            d1 += __shfl_xor(d1, off);
            d2 += __shfl_xor(d2, off);
            d3 += __shfl_xor(d3, off);
        }
        float a0 = d0 * SC, a1 = d1 * SC, a2 = d2 * SC, a3 = d3 * SC;
        float mm = fmaxf(fmaxf(a0, a1), fmaxf(a2, a3));
        float newm = fmaxf(m, mm);
        float scale = __expf(m - newm);
        float w0 = __expf(a0 - newm), w1 = __expf(a1 - newm);
        float w2 = __expf(a2 - newm), w3 = __expf(a3 - newm);
        s  = s  * scale + ((w0 + w1) + (w2 + w3));
        ax = ax * scale + ((w0 * f0.x + w1 * f1.x) + (w2 * f2.x + w3 * f3.x));
        ay = ay * scale + ((w0 * f0.y + w1 * f1.y) + (w2 * f2.y + w3 * f3.y));
        m = newm;
    }
    for (; p < end; ++p) {
        int h = hes[p];
        float2 f2 = ((const float2*)he_feat)[(size_t)h * 64 + lane];
        float d = q2.x * f2.x + q2.y * f2.y;
        d += __shfl_xor(d, 1);
        d += __shfl_xor(d, 2);
        d += __shfl_xor(d, 4);
        d += __shfl_xor(d, 8);
        float a = d * SC;
        float newm = fmaxf(m, a);
        float scale = __expf(m - newm);
        float w = __expf(a - newm);
        s  = s  * scale + w;
        ax = ax * scale + w * f2.x;
        ay = ay * scale + w * f2.y;
        m = newm;
    }
    float inv = 1.f / (s + 1e-16f);
    ((float2*)node_out)[(size_t)n * 64 + lane] = make_float2(ax * inv, ay * inv);
}

// ---------------------------------------------------------------------------
extern "C" void kernel_launch(void* const* d_in, const int* in_sizes, int n_in,
                              void* d_out, int out_size, void* d_ws, size_t ws_size,
                              hipStream_t stream)
{
    const float* x        = (const float*)d_in[0];
    const int*   node_idx = (const int*)d_in[1];
    const int*   he_idx   = (const int*)d_in[2];
    const float* Wk       = (const float*)d_in[3];
    const float* bk       = (const float*)d_in[4];
    const float* Wq       = (const float*)d_in[5];
    const float* bq       = (const float*)d_in[6];
    const float* Wa       = (const float*)d_in[7];
    const float* ba       = (const float*)d_in[8];
    float*       out      = (float*)d_out;

    const int N = in_sizes[0] / D;
    const int E = in_sizes[1];

    // Workspace layout. Kbuf reused as node_out after gather_he consumes K.
    float* ws      = (float*)d_ws;
    float* Kbuf    = ws;                               // N*D  (later node_out)
    float* Qbuf    = Kbuf    + (size_t)N * D;          // N*D
    float* he_feat = Qbuf    + (size_t)N * D;          // NUM_HE*D
    unsigned short* wfrag = (unsigned short*)(he_feat + (size_t)NUM_HE * D); // 3*32768
    int*   ibase   = (int*)(wfrag + 3 * 32768);
    int*   he_ptr  = ibase;                            // NUM_HE+1
    int*   he_cur  = he_ptr  + (NUM_HE + 1);           // NUM_HE
    int*   he_mem  = he_cur  + NUM_HE;                 // E (node ids by he)
    int*   nd_ptr  = he_mem  + E;                      // N+1
    int*   nd_cur  = nd_ptr  + (N + 1);                // N
    int*   nd_he   = nd_cur  + N;                      // E (he ids by node)
    int*   partial = nd_he   + E;                      // 256

    const int gemm_grid = (N + 127) / 128;

    // W fragments (hi/lo) for all three projections
    wprep<<<(3 * 16384 + 255) / 256, 256, 0, stream>>>(Wk, Wq, Wa, wfrag);

    // Stage 1: K, Q projections (split-bf16 MFMA)
    gemm_split<false><<<gemm_grid, 256, 0, stream>>>(
        x, nullptr, wfrag, wfrag + 16384, bk, Kbuf, N);
    gemm_split<false><<<gemm_grid, 256, 0, stream>>>(
        x, nullptr, wfrag + 32768, wfrag + 49152, bq, Qbuf, N);

    // CSR by hyperedge
    {
        const int npb = (NUM_HE + 1023) / 1024;
        hipMemsetAsync(he_cur, 0, sizeof(int) * NUM_HE, stream);
        hist_kernel<<<(E + 255) / 256, 256, 0, stream>>>(he_idx, he_cur, E);
        scan_block<<<npb, 1024, 0, stream>>>(he_cur, he_ptr, partial, NUM_HE);
        scan_partials<<<1, 128, 0, stream>>>(partial, he_ptr + NUM_HE, npb);
        scan_add<<<(NUM_HE + 255) / 256, 256, 0, stream>>>(he_ptr, he_cur, partial, NUM_HE);
        csr_fill<<<(E + 255) / 256, 256, 0, stream>>>(he_idx, node_idx, he_cur, he_mem, E);
    }

    // CSR by node
    {
        const int npb = (N + 1023) / 1024;
        hipMemsetAsync(nd_cur, 0, sizeof(int) * N, stream);
        hist_kernel<<<(E + 255) / 256, 256, 0, stream>>>(node_idx, nd_cur, E);
        scan_block<<<npb, 1024, 0, stream>>>(nd_cur, nd_ptr, partial, N);
        scan_partials<<<1, 128, 0, stream>>>(partial, nd_ptr + N, npb);
        scan_add<<<(N + 255) / 256, 256, 0, stream>>>(nd_ptr, nd_cur, partial, N);
        csr_fill<<<(E + 255) / 256, 256, 0, stream>>>(node_idx, he_idx, nd_cur, nd_he, E);
    }

    // Stage 2: hyperedge aggregation (gather, 4x ILP)
    gather_he<<<(NUM_HE + 3) / 4, 256, 0, stream>>>(Kbuf, he_ptr, he_mem, he_feat, NUM_HE);

    // Stages 3-5: fused attention (K consumed; Kbuf becomes node_out)
    fused_attn<<<(N + 3) / 4, 256, 0, stream>>>(Qbuf, he_feat, nd_ptr, nd_he, Kbuf, N);

    // Stage 6: residual folded into A-load; split-bf16 MFMA
    gemm_split<true><<<gemm_grid, 256, 0, stream>>>(
        Kbuf, x, wfrag + 65536, wfrag + 81920, ba, out, N);
}

// Round 5
// 485.286 us; speedup vs baseline: 2.7726x; 1.0973x over previous
//
#include <hip/hip_runtime.h>
#include <math.h>

#define D 128
#define HEADS 4
#define DK 32
#define NUM_HE 20000

typedef short bf16x8 __attribute__((ext_vector_type(8)));
typedef float f32x4  __attribute__((ext_vector_type(4)));

__device__ __forceinline__ unsigned short f2bf(float f) {
    unsigned int u = __float_as_uint(f);
    u = (u + 0x7fffu + ((u >> 16) & 1u)) >> 16;
    return (unsigned short)u;
}
__device__ __forceinline__ float bf2f(unsigned short h) {
    return __uint_as_float(((unsigned int)h) << 16);
}
// unpack 2 bf16 packed in a uint (lo = even dim, hi = odd dim)
__device__ __forceinline__ float bflo(unsigned int u) {
    return __uint_as_float(u << 16);
}
__device__ __forceinline__ float bfhi(unsigned int u) {
    return __uint_as_float(u & 0xffff0000u);
}

// ---------------------------------------------------------------------------
// W preprocessing: fragment-order Wk|Wq|Wa as bf16 hi/lo.
// ---------------------------------------------------------------------------
__global__ void wprep(const float* __restrict__ Wk, const float* __restrict__ Wq,
                      const float* __restrict__ Wa, unsigned short* __restrict__ dst)
{
    int t = blockIdx.x * blockDim.x + threadIdx.x;
    if (t >= 3 * 16384) return;
    int w = t >> 14, rem = t & 16383;
    int ks = rem >> 12, nf = (rem >> 9) & 7, lane = (rem >> 3) & 63, j = rem & 7;
    int r = ks * 32 + (lane >> 4) * 8 + j;
    int c = nf * 16 + (lane & 15);
    const float* W = (w == 0) ? Wk : (w == 1) ? Wq : Wa;
    float v = W[r * 128 + c];
    unsigned short h = f2bf(v);
    dst[(size_t)w * 32768 + rem]         = h;
    dst[(size_t)w * 32768 + 16384 + rem] = f2bf(v - bf2f(h));
}

// ---------------------------------------------------------------------------
// Split-bf16 MFMA GEMM: C[M,128] = (A (+R)) @ W + bias, W pre-fragmented.
// OUTBF: store C as bf16 (ushort) instead of fp32.
// ---------------------------------------------------------------------------
template<bool RES, bool OUTBF>
__global__ __launch_bounds__(256) void gemm_split(
    const float* __restrict__ A, const float* __restrict__ R,
    const unsigned short* __restrict__ Bh, const unsigned short* __restrict__ Bl,
    const float* __restrict__ bias, float* __restrict__ C, int M)
{
    const int lane = threadIdx.x & 63;
    const int wv   = threadIdx.x >> 6;
    const int r0   = blockIdx.x * 128 + wv * 32;
    const int lr   = lane & 15;
    const int kg   = lane >> 4;

    f32x4 acc[2][8];
    #pragma unroll
    for (int m = 0; m < 2; ++m)
        #pragma unroll
        for (int n = 0; n < 8; ++n) acc[m][n] = (f32x4){0.f, 0.f, 0.f, 0.f};

    int row[2];
    row[0] = min(r0 + lr,      M - 1);
    row[1] = min(r0 + 16 + lr, M - 1);

    for (int ks = 0; ks < 4; ++ks) {
        bf16x8 ah[2], al[2];
        #pragma unroll
        for (int m = 0; m < 2; ++m) {
            const float* p = A + (size_t)row[m] * D + ks * 32 + kg * 8;
            float4 v0 = *(const float4*)p;
            float4 v1 = *(const float4*)(p + 4);
            float vv[8] = {v0.x, v0.y, v0.z, v0.w, v1.x, v1.y, v1.z, v1.w};
            if (RES) {
                const float* q = R + (size_t)row[m] * D + ks * 32 + kg * 8;
                float4 u0 = *(const float4*)q;
                float4 u1 = *(const float4*)(q + 4);
                vv[0] += u0.x; vv[1] += u0.y; vv[2] += u0.z; vv[3] += u0.w;
                vv[4] += u1.x; vv[5] += u1.y; vv[6] += u1.z; vv[7] += u1.w;
            }
            #pragma unroll
            for (int j = 0; j < 8; ++j) {
                unsigned short h = f2bf(vv[j]);
                ah[m][j] = (short)h;
                al[m][j] = (short)f2bf(vv[j] - bf2f(h));
            }
        }
        #pragma unroll
        for (int nf = 0; nf < 8; ++nf) {
            const int boff = ((ks * 8 + nf) * 64 + lane) * 8;
            bf16x8 bh = *(const bf16x8*)(const void*)(Bh + boff);
            bf16x8 bl = *(const bf16x8*)(const void*)(Bl + boff);
            #pragma unroll
            for (int m = 0; m < 2; ++m) {
                acc[m][nf] = __builtin_amdgcn_mfma_f32_16x16x32_bf16(ah[m], bh, acc[m][nf], 0, 0, 0);
                acc[m][nf] = __builtin_amdgcn_mfma_f32_16x16x32_bf16(ah[m], bl, acc[m][nf], 0, 0, 0);
                acc[m][nf] = __builtin_amdgcn_mfma_f32_16x16x32_bf16(al[m], bh, acc[m][nf], 0, 0, 0);
            }
        }
    }

    #pragma unroll
    for (int nf = 0; nf < 8; ++nf) {
        int col = nf * 16 + lr;
        float bv = bias[col];
        #pragma unroll
        for (int m = 0; m < 2; ++m) {
            #pragma unroll
            for (int j = 0; j < 4; ++j) {
                int gr = r0 + m * 16 + kg * 4 + j;
                if (gr < M) {
                    float v = acc[m][nf][j] + bv;
                    if (OUTBF) ((unsigned short*)C)[(size_t)gr * D + col] = f2bf(v);
                    else       C[(size_t)gr * D + col] = v;
                }
            }
        }
    }
}

// ---------------------------------------------------------------------------
// CSR construction: histogram -> 3-phase multi-block exclusive scan -> fill
// ---------------------------------------------------------------------------
__global__ void hist_kernel(const int* __restrict__ seg, int* __restrict__ cnt, int E)
{
    int e = blockIdx.x * blockDim.x + threadIdx.x;
    if (e < E) atomicAdd(&cnt[seg[e]], 1);
}

__global__ void scan_block(const int* __restrict__ cnt, int* __restrict__ excl,
                           int* __restrict__ partials, int n)
{
    __shared__ int wsum[16];
    const int tid  = threadIdx.x;
    const int lane = tid & 63;
    const int wid  = tid >> 6;
    int i = blockIdx.x * 1024 + tid;
    int v = (i < n) ? cnt[i] : 0;
    int x = v;
    #pragma unroll
    for (int off = 1; off < 64; off <<= 1) {
        int y = __shfl_up(x, off);
        if (lane >= off) x += y;
    }
    if (lane == 63) wsum[wid] = x;
    __syncthreads();
    if (wid == 0) {
        int wv = (lane < 16) ? wsum[lane] : 0;
        #pragma unroll
        for (int off = 1; off < 16; off <<= 1) {
            int y = __shfl_up(wv, off);
            if (lane >= off) wv += y;
        }
        if (lane < 16) wsum[lane] = wv;
    }
    __syncthreads();
    int base = (wid > 0) ? wsum[wid - 1] : 0;
    if (i < n) excl[i] = base + x - v;
    if (tid == 1023) partials[blockIdx.x] = base + x;
}

__global__ void scan_partials(int* __restrict__ partials, int* __restrict__ total, int np)
{
    __shared__ int ws[2];
    const int tid = threadIdx.x, lane = tid & 63, wid = tid >> 6;
    int v = (tid < np) ? partials[tid] : 0;
    int x = v;
    #pragma unroll
    for (int off = 1; off < 64; off <<= 1) {
        int y = __shfl_up(x, off);
        if (lane >= off) x += y;
    }
    if (lane == 63) ws[wid] = x;
    __syncthreads();
    int incl = x + ((wid == 1) ? ws[0] : 0);
    if (tid < np) partials[tid] = incl - v;
    if (tid == np - 1) *total = incl;
}

__global__ void scan_add(int* __restrict__ ptr, int* __restrict__ cursor,
                         const int* __restrict__ partials, int n)
{
    int i = blockIdx.x * blockDim.x + threadIdx.x;
    if (i >= n) return;
    int v = ptr[i] + partials[i >> 10];
    ptr[i] = v;
    cursor[i] = v;
}

__global__ void csr_fill(const int* __restrict__ seg, const int* __restrict__ val,
                         int* __restrict__ cursor, int* __restrict__ out, int E)
{
    int e = blockIdx.x * blockDim.x + threadIdx.x;
    if (e >= E) return;
    int pos = atomicAdd(&cursor[seg[e]], 1);
    out[pos] = val[e];
}

// ---------------------------------------------------------------------------
// Stage 2: he_feat[h] = sum of member K rows. K and he_feat in bf16
// (uint = 2 packed bf16 per lane); fp32 accumulate. 4x ILP.
// ---------------------------------------------------------------------------
__global__ void gather_he(const unsigned int* __restrict__ K,
                          const int* __restrict__ he_ptr,
                          const int* __restrict__ members,
                          unsigned int* __restrict__ he_feat, int HE)
{
    int h = blockIdx.x * 4 + (threadIdx.x >> 6);
    int lane = threadIdx.x & 63;
    if (h >= HE) return;
    int beg = he_ptr[h], end = he_ptr[h + 1];
    float ax = 0.f, ay = 0.f;
    int p = beg;
    for (; p + 3 < end; p += 4) {
        int n0 = members[p],     n1 = members[p + 1];
        int n2 = members[p + 2], n3 = members[p + 3];
        unsigned int k0 = K[(size_t)n0 * 64 + lane];
        unsigned int k1 = K[(size_t)n1 * 64 + lane];
        unsigned int k2 = K[(size_t)n2 * 64 + lane];
        unsigned int k3 = K[(size_t)n3 * 64 + lane];
        ax += (bflo(k0) + bflo(k1)) + (bflo(k2) + bflo(k3));
        ay += (bfhi(k0) + bfhi(k1)) + (bfhi(k2) + bfhi(k3));
    }
    for (; p < end; ++p) {
        int n = members[p];
        unsigned int k = K[(size_t)n * 64 + lane];
        ax += bflo(k); ay += bfhi(k);
    }
    he_feat[(size_t)h * 64 + lane] =
        (unsigned int)f2bf(ax) | ((unsigned int)f2bf(ay) << 16);
}

// ---------------------------------------------------------------------------
// Stages 3-5 fused: per-node online softmax + weighted accumulate, 4x ILP.
// Q fp32, he_feat bf16 (uint loads). node_out fp32.
// ---------------------------------------------------------------------------
__global__ void fused_attn(const float* __restrict__ Q,
                           const unsigned int* __restrict__ he_feat,
                           const int* __restrict__ node_ptr,
                           const int* __restrict__ hes,
                           float* __restrict__ node_out, int N)
{
    const float SC = 0.17677669529663687f;   // 1/sqrt(32)
    int n = blockIdx.x * 4 + (threadIdx.x >> 6);
    int lane = threadIdx.x & 63;
    if (n >= N) return;
    int beg = node_ptr[n], end = node_ptr[n + 1];
    float2 q2 = ((const float2*)Q)[(size_t)n * 64 + lane];
    float m = -INFINITY, s = 0.f, ax = 0.f, ay = 0.f;

    int p = beg;
    for (; p + 3 < end; p += 4) {
        int h0 = hes[p],     h1 = hes[p + 1];
        int h2 = hes[p + 2], h3 = hes[p + 3];
        unsigned int u0 = he_feat[(size_t)h0 * 64 + lane];
        unsigned int u1 = he_feat[(size_t)h1 * 64 + lane];
        unsigned int u2 = he_feat[(size_t)h2 * 64 + lane];
        unsigned int u3 = he_feat[(size_t)h3 * 64 + lane];
        float f0x = bflo(u0), f0y = bfhi(u0);
        float f1x = bflo(u1), f1y = bfhi(u1);
        float f2x = bflo(u2), f2y = bfhi(u2);
        float f3x = bflo(u3), f3y = bfhi(u3);
        float d0 = q2.x * f0x + q2.y * f0y;
        float d1 = q2.x * f1x + q2.y * f1y;
        float d2 = q2.x * f2x + q2.y * f2y;
        float d3 = q2.x * f3x + q2.y * f3y;
        #pragma unroll
        for (int off = 1; off <= 8; off <<= 1) {
            d0 += __shfl_xor(d0, off);
            d1 += __shfl_xor(d1, off);
            d2 += __shfl_xor(d2, off);
            d3 += __shfl_xor(d3, off);
        }
        float a0 = d0 * SC, a1 = d1 * SC, a2 = d2 * SC, a3 = d3 * SC;
        float mm = fmaxf(fmaxf(a0, a1), fmaxf(a2, a3));
        float newm = fmaxf(m, mm);
        float scale = __expf(m - newm);
        float w0 = __expf(a0 - newm), w1 = __expf(a1 - newm);
        float w2 = __expf(a2 - newm), w3 = __expf(a3 - newm);
        s  = s  * scale + ((w0 + w1) + (w2 + w3));
        ax = ax * scale + ((w0 * f0x + w1 * f1x) + (w2 * f2x + w3 * f3x));
        ay = ay * scale + ((w0 * f0y + w1 * f1y) + (w2 * f2y + w3 * f3y));
        m = newm;
    }
    for (; p < end; ++p) {
        int h = hes[p];
        unsigned int u = he_feat[(size_t)h * 64 + lane];
        float fx = bflo(u), fy = bfhi(u);
        float d = q2.x * fx + q2.y * fy;
        d += __shfl_xor(d, 1);
        d += __shfl_xor(d, 2);
        d += __shfl_xor(d, 4);
        d += __shfl_xor(d, 8);
        float a = d * SC;
        float newm = fmaxf(m, a);
        float scale = __expf(m - newm);
        float w = __expf(a - newm);
        s  = s  * scale + w;
        ax = ax * scale + w * fx;
        ay = ay * scale + w * fy;
        m = newm;
    }
    float inv = 1.f / (s + 1e-16f);
    ((float2*)node_out)[(size_t)n * 64 + lane] = make_float2(ax * inv, ay * inv);
}

// ---------------------------------------------------------------------------
extern "C" void kernel_launch(void* const* d_in, const int* in_sizes, int n_in,
                              void* d_out, int out_size, void* d_ws, size_t ws_size,
                              hipStream_t stream)
{
    const float* x        = (const float*)d_in[0];
    const int*   node_idx = (const int*)d_in[1];
    const int*   he_idx   = (const int*)d_in[2];
    const float* Wk       = (const float*)d_in[3];
    const float* bk       = (const float*)d_in[4];
    const float* Wq       = (const float*)d_in[5];
    const float* bq       = (const float*)d_in[6];
    const float* Wa       = (const float*)d_in[7];
    const float* ba       = (const float*)d_in[8];
    float*       out      = (float*)d_out;

    const int N = in_sizes[0] / D;
    const int E = in_sizes[1];

    // Workspace layout (regions sized in fp32 units; K/he_feat use bf16
    // inside their regions). Kbuf region reused as fp32 node_out after
    // gather_he consumes the bf16 K.
    float* ws      = (float*)d_ws;
    float* Kbuf    = ws;                               // N*D f32 region (bf16 K / later f32 node_out)
    float* Qbuf    = Kbuf    + (size_t)N * D;          // N*D f32 (Q)
    float* he_feat = Qbuf    + (size_t)N * D;          // NUM_HE*D region (bf16 used half)
    unsigned short* wfrag = (unsigned short*)(he_feat + (size_t)NUM_HE * D); // 3*32768
    int*   ibase   = (int*)(wfrag + 3 * 32768);
    int*   he_ptr  = ibase;                            // NUM_HE+1
    int*   he_cur  = he_ptr  + (NUM_HE + 1);           // NUM_HE
    int*   he_mem  = he_cur  + NUM_HE;                 // E
    int*   nd_ptr  = he_mem  + E;                      // N+1
    int*   nd_cur  = nd_ptr  + (N + 1);                // N
    int*   nd_he   = nd_cur  + N;                      // E
    int*   partial = nd_he   + E;                      // 256

    const int gemm_grid = (N + 127) / 128;

    // W fragments (hi/lo) for all three projections
    wprep<<<(3 * 16384 + 255) / 256, 256, 0, stream>>>(Wk, Wq, Wa, wfrag);

    // Stage 1: K (bf16 out), Q (fp32 out) projections
    gemm_split<false, true><<<gemm_grid, 256, 0, stream>>>(
        x, nullptr, wfrag, wfrag + 16384, bk, Kbuf, N);
    gemm_split<false, false><<<gemm_grid, 256, 0, stream>>>(
        x, nullptr, wfrag + 32768, wfrag + 49152, bq, Qbuf, N);

    // CSR by hyperedge
    {
        const int npb = (NUM_HE + 1023) / 1024;
        hipMemsetAsync(he_cur, 0, sizeof(int) * NUM_HE, stream);
        hist_kernel<<<(E + 255) / 256, 256, 0, stream>>>(he_idx, he_cur, E);
        scan_block<<<npb, 1024, 0, stream>>>(he_cur, he_ptr, partial, NUM_HE);
        scan_partials<<<1, 128, 0, stream>>>(partial, he_ptr + NUM_HE, npb);
        scan_add<<<(NUM_HE + 255) / 256, 256, 0, stream>>>(he_ptr, he_cur, partial, NUM_HE);
        csr_fill<<<(E + 255) / 256, 256, 0, stream>>>(he_idx, node_idx, he_cur, he_mem, E);
    }

    // CSR by node
    {
        const int npb = (N + 1023) / 1024;
        hipMemsetAsync(nd_cur, 0, sizeof(int) * N, stream);
        hist_kernel<<<(E + 255) / 256, 256, 0, stream>>>(node_idx, nd_cur, E);
        scan_block<<<npb, 1024, 0, stream>>>(nd_cur, nd_ptr, partial, N);
        scan_partials<<<1, 128, 0, stream>>>(partial, nd_ptr + N, npb);
        scan_add<<<(N + 255) / 256, 256, 0, stream>>>(nd_ptr, nd_cur, partial, N);
        csr_fill<<<(E + 255) / 256, 256, 0, stream>>>(node_idx, he_idx, nd_cur, nd_he, E);
    }

    // Stage 2: hyperedge aggregation (bf16 gather)
    gather_he<<<(NUM_HE + 3) / 4, 256, 0, stream>>>(
        (const unsigned int*)Kbuf, he_ptr, he_mem, (unsigned int*)he_feat, NUM_HE);

    // Stages 3-5: fused attention (bf16 K dead; Kbuf region becomes f32 node_out)
    fused_attn<<<(N + 3) / 4, 256, 0, stream>>>(
        Qbuf, (const unsigned int*)he_feat, nd_ptr, nd_he, Kbuf, N);

    // Stage 6: residual folded into A-load; fp32 out
    gemm_split<true, false><<<gemm_grid, 256, 0, stream>>>(
        Kbuf, x, wfrag + 65536, wfrag + 81920, ba, out, N);
}

// Round 6
// 421.536 us; speedup vs baseline: 3.1920x; 1.1512x over previous
//
#include <hip/hip_runtime.h>
#include <math.h>

#define D 128
#define HEADS 4
#define DK 32
#define NUM_HE 20000

typedef short bf16x8 __attribute__((ext_vector_type(8)));
typedef float f32x4  __attribute__((ext_vector_type(4)));

__device__ __forceinline__ unsigned short f2bf(float f) {
    unsigned int u = __float_as_uint(f);
    u = (u + 0x7fffu + ((u >> 16) & 1u)) >> 16;
    return (unsigned short)u;
}
__device__ __forceinline__ float bf2f(unsigned short h) {
    return __uint_as_float(((unsigned int)h) << 16);
}
__device__ __forceinline__ float bflo(unsigned int u) {
    return __uint_as_float(u << 16);
}
__device__ __forceinline__ float bfhi(unsigned int u) {
    return __uint_as_float(u & 0xffff0000u);
}

// ---------------------------------------------------------------------------
// W preprocessing: fragment-order Wk|Wq|Wa as bf16 hi/lo.
// ---------------------------------------------------------------------------
__global__ void wprep(const float* __restrict__ Wk, const float* __restrict__ Wq,
                      const float* __restrict__ Wa, unsigned short* __restrict__ dst)
{
    int t = blockIdx.x * blockDim.x + threadIdx.x;
    if (t >= 3 * 16384) return;
    int w = t >> 14, rem = t & 16383;
    int ks = rem >> 12, nf = (rem >> 9) & 7, lane = (rem >> 3) & 63, j = rem & 7;
    int r = ks * 32 + (lane >> 4) * 8 + j;
    int c = nf * 16 + (lane & 15);
    const float* W = (w == 0) ? Wk : (w == 1) ? Wq : Wa;
    float v = W[r * 128 + c];
    unsigned short h = f2bf(v);
    dst[(size_t)w * 32768 + rem]         = h;
    dst[(size_t)w * 32768 + 16384 + rem] = f2bf(v - bf2f(h));
}

// ---------------------------------------------------------------------------
// Split-bf16 MFMA GEMM: C[M,128] = (A (+R)) @ W + bias, W pre-fragmented.
// ---------------------------------------------------------------------------
template<bool RES, bool OUTBF>
__global__ __launch_bounds__(256) void gemm_split(
    const float* __restrict__ A, const float* __restrict__ R,
    const unsigned short* __restrict__ Bh, const unsigned short* __restrict__ Bl,
    const float* __restrict__ bias, float* __restrict__ C, int M)
{
    const int lane = threadIdx.x & 63;
    const int wv   = threadIdx.x >> 6;
    const int r0   = blockIdx.x * 128 + wv * 32;
    const int lr   = lane & 15;
    const int kg   = lane >> 4;

    f32x4 acc[2][8];
    #pragma unroll
    for (int m = 0; m < 2; ++m)
        #pragma unroll
        for (int n = 0; n < 8; ++n) acc[m][n] = (f32x4){0.f, 0.f, 0.f, 0.f};

    int row[2];
    row[0] = min(r0 + lr,      M - 1);
    row[1] = min(r0 + 16 + lr, M - 1);

    for (int ks = 0; ks < 4; ++ks) {
        bf16x8 ah[2], al[2];
        #pragma unroll
        for (int m = 0; m < 2; ++m) {
            const float* p = A + (size_t)row[m] * D + ks * 32 + kg * 8;
            float4 v0 = *(const float4*)p;
            float4 v1 = *(const float4*)(p + 4);
            float vv[8] = {v0.x, v0.y, v0.z, v0.w, v1.x, v1.y, v1.z, v1.w};
            if (RES) {
                const float* q = R + (size_t)row[m] * D + ks * 32 + kg * 8;
                float4 u0 = *(const float4*)q;
                float4 u1 = *(const float4*)(q + 4);
                vv[0] += u0.x; vv[1] += u0.y; vv[2] += u0.z; vv[3] += u0.w;
                vv[4] += u1.x; vv[5] += u1.y; vv[6] += u1.z; vv[7] += u1.w;
            }
            #pragma unroll
            for (int j = 0; j < 8; ++j) {
                unsigned short h = f2bf(vv[j]);
                ah[m][j] = (short)h;
                al[m][j] = (short)f2bf(vv[j] - bf2f(h));
            }
        }
        #pragma unroll
        for (int nf = 0; nf < 8; ++nf) {
            const int boff = ((ks * 8 + nf) * 64 + lane) * 8;
            bf16x8 bh = *(const bf16x8*)(const void*)(Bh + boff);
            bf16x8 bl = *(const bf16x8*)(const void*)(Bl + boff);
            #pragma unroll
            for (int m = 0; m < 2; ++m) {
                acc[m][nf] = __builtin_amdgcn_mfma_f32_16x16x32_bf16(ah[m], bh, acc[m][nf], 0, 0, 0);
                acc[m][nf] = __builtin_amdgcn_mfma_f32_16x16x32_bf16(ah[m], bl, acc[m][nf], 0, 0, 0);
                acc[m][nf] = __builtin_amdgcn_mfma_f32_16x16x32_bf16(al[m], bh, acc[m][nf], 0, 0, 0);
            }
        }
    }

    #pragma unroll
    for (int nf = 0; nf < 8; ++nf) {
        int col = nf * 16 + lr;
        float bv = bias[col];
        #pragma unroll
        for (int m = 0; m < 2; ++m) {
            #pragma unroll
            for (int j = 0; j < 4; ++j) {
                int gr = r0 + m * 16 + kg * 4 + j;
                if (gr < M) {
                    float v = acc[m][nf][j] + bv;
                    if (OUTBF) ((unsigned short*)C)[(size_t)gr * D + col] = f2bf(v);
                    else       C[(size_t)gr * D + col] = v;
                }
            }
        }
    }
}

// ---------------------------------------------------------------------------
// CSR construction: histogram -> 3-phase scan -> bucket-binned fill
// ---------------------------------------------------------------------------
__global__ void hist_kernel(const int* __restrict__ seg, int* __restrict__ cnt, int E)
{
    int e = blockIdx.x * blockDim.x + threadIdx.x;
    if (e < E) atomicAdd(&cnt[seg[e]], 1);
}

__global__ void scan_block(const int* __restrict__ cnt, int* __restrict__ excl,
                           int* __restrict__ partials, int n)
{
    __shared__ int wsum[16];
    const int tid  = threadIdx.x;
    const int lane = tid & 63;
    const int wid  = tid >> 6;
    int i = blockIdx.x * 1024 + tid;
    int v = (i < n) ? cnt[i] : 0;
    int x = v;
    #pragma unroll
    for (int off = 1; off < 64; off <<= 1) {
        int y = __shfl_up(x, off);
        if (lane >= off) x += y;
    }
    if (lane == 63) wsum[wid] = x;
    __syncthreads();
    if (wid == 0) {
        int wv = (lane < 16) ? wsum[lane] : 0;
        #pragma unroll
        for (int off = 1; off < 16; off <<= 1) {
            int y = __shfl_up(wv, off);
            if (lane >= off) wv += y;
        }
        if (lane < 16) wsum[lane] = wv;
    }
    __syncthreads();
    int base = (wid > 0) ? wsum[wid - 1] : 0;
    if (i < n) excl[i] = base + x - v;
    if (tid == 1023) partials[blockIdx.x] = base + x;
}

__global__ void scan_partials(int* __restrict__ partials, int* __restrict__ total, int np)
{
    __shared__ int ws[2];
    const int tid = threadIdx.x, lane = tid & 63, wid = tid >> 6;
    int v = (tid < np) ? partials[tid] : 0;
    int x = v;
    #pragma unroll
    for (int off = 1; off < 64; off <<= 1) {
        int y = __shfl_up(x, off);
        if (lane >= off) x += y;
    }
    if (lane == 63) ws[wid] = x;
    __syncthreads();
    int incl = x + ((wid == 1) ? ws[0] : 0);
    if (tid < np) partials[tid] = incl - v;
    if (tid == np - 1) *total = incl;
}

__global__ void scan_add(int* __restrict__ ptr, const int* __restrict__ partials, int n)
{
    int i = blockIdx.x * blockDim.x + threadIdx.x;
    if (i >= n) return;
    ptr[i] += partials[i >> 10];
}

// bucket cursors start at ptr[b<<SHIFT]
template<int SHIFT>
__global__ void init_bcur(const int* __restrict__ ptr, int* __restrict__ bcur,
                          int nseg, int nb)
{
    int b = blockIdx.x * blockDim.x + threadIdx.x;
    if (b < nb) bcur[b] = ptr[min(b << SHIFT, nseg)];
}

// Pass 1: bin (seg,val) pairs into bucket-contiguous staging.
// Block handles 4096 entries; LDS histogram + rank, one global atomic per
// (block,bucket) to reserve a run, then 8B writes into the run.
#define BIN_CH 4096
template<int SHIFT, int MAXNB>
__global__ __launch_bounds__(256) void bin_pairs(
    const int* __restrict__ seg, const int* __restrict__ val,
    int* __restrict__ bcur, uint2* __restrict__ staging, int E, int nb)
{
    __shared__ int hist[MAXNB];
    __shared__ int base[MAXNB];
    const int tid = threadIdx.x;
    const int e0  = blockIdx.x * BIN_CH;
    for (int i = tid; i < nb; i += 256) hist[i] = 0;
    __syncthreads();
    int myseg[16], myval[16], myrank[16];
    #pragma unroll
    for (int j = 0; j < 16; ++j) {
        int e = e0 + j * 256 + tid;
        if (e < E) {
            int s = seg[e];
            myseg[j]  = s;
            myval[j]  = val[e];
            myrank[j] = atomicAdd(&hist[s >> SHIFT], 1);
        } else myseg[j] = -1;
    }
    __syncthreads();
    for (int i = tid; i < nb; i += 256) {
        int c = hist[i];
        base[i] = c ? atomicAdd(&bcur[i], c) : 0;
    }
    __syncthreads();
    #pragma unroll
    for (int j = 0; j < 16; ++j) {
        if (myseg[j] >= 0) {
            int b = myseg[j] >> SHIFT;
            staging[base[b] + myrank[j]] = make_uint2((unsigned)myseg[j], (unsigned)myval[j]);
        }
    }
}

// Pass 2: one block per bucket; per-seg cursors in LDS; dense local writes.
template<int SHIFT>
__global__ __launch_bounds__(256) void fill_from_bins(
    const uint2* __restrict__ staging, const int* __restrict__ ptr,
    int* __restrict__ outv, int nseg)
{
    __shared__ int cur[1 << SHIFT];
    const int b  = blockIdx.x;
    const int s0 = b << SHIFT;
    const int s1 = min(s0 + (1 << SHIFT), nseg);
    for (int i = threadIdx.x; i < s1 - s0; i += 256) cur[i] = ptr[s0 + i];
    __syncthreads();
    const int beg = ptr[s0], end = ptr[s1];
    for (int p = beg + threadIdx.x; p < end; p += 256) {
        uint2 pv = staging[p];
        int pos = atomicAdd(&cur[(int)pv.x - s0], 1);
        outv[pos] = (int)pv.y;
    }
}

// ---------------------------------------------------------------------------
// Stage 2: he_feat[h] = sum of member K rows (bf16 in/out, f32 accum, 4x ILP)
// ---------------------------------------------------------------------------
__global__ void gather_he(const unsigned int* __restrict__ K,
                          const int* __restrict__ he_ptr,
                          const int* __restrict__ members,
                          unsigned int* __restrict__ he_feat, int HE)
{
    int h = blockIdx.x * 4 + (threadIdx.x >> 6);
    int lane = threadIdx.x & 63;
    if (h >= HE) return;
    int beg = he_ptr[h], end = he_ptr[h + 1];
    float ax = 0.f, ay = 0.f;
    int p = beg;
    for (; p + 3 < end; p += 4) {
        int n0 = members[p],     n1 = members[p + 1];
        int n2 = members[p + 2], n3 = members[p + 3];
        unsigned int k0 = K[(size_t)n0 * 64 + lane];
        unsigned int k1 = K[(size_t)n1 * 64 + lane];
        unsigned int k2 = K[(size_t)n2 * 64 + lane];
        unsigned int k3 = K[(size_t)n3 * 64 + lane];
        ax += (bflo(k0) + bflo(k1)) + (bflo(k2) + bflo(k3));
        ay += (bfhi(k0) + bfhi(k1)) + (bfhi(k2) + bfhi(k3));
    }
    for (; p < end; ++p) {
        int n = members[p];
        unsigned int k = K[(size_t)n * 64 + lane];
        ax += bflo(k); ay += bfhi(k);
    }
    he_feat[(size_t)h * 64 + lane] =
        (unsigned int)f2bf(ax) | ((unsigned int)f2bf(ay) << 16);
}

// ---------------------------------------------------------------------------
// Stages 3-5 fused: per-node online softmax + weighted accumulate, 4x ILP.
// ---------------------------------------------------------------------------
__global__ void fused_attn(const float* __restrict__ Q,
                           const unsigned int* __restrict__ he_feat,
                           const int* __restrict__ node_ptr,
                           const int* __restrict__ hes,
                           float* __restrict__ node_out, int N)
{
    const float SC = 0.17677669529663687f;   // 1/sqrt(32)
    int n = blockIdx.x * 4 + (threadIdx.x >> 6);
    int lane = threadIdx.x & 63;
    if (n >= N) return;
    int beg = node_ptr[n], end = node_ptr[n + 1];
    float2 q2 = ((const float2*)Q)[(size_t)n * 64 + lane];
    float m = -INFINITY, s = 0.f, ax = 0.f, ay = 0.f;

    int p = beg;
    for (; p + 3 < end; p += 4) {
        int h0 = hes[p],     h1 = hes[p + 1];
        int h2 = hes[p + 2], h3 = hes[p + 3];
        unsigned int u0 = he_feat[(size_t)h0 * 64 + lane];
        unsigned int u1 = he_feat[(size_t)h1 * 64 + lane];
        unsigned int u2 = he_feat[(size_t)h2 * 64 + lane];
        unsigned int u3 = he_feat[(size_t)h3 * 64 + lane];
        float f0x = bflo(u0), f0y = bfhi(u0);
        float f1x = bflo(u1), f1y = bfhi(u1);
        float f2x = bflo(u2), f2y = bfhi(u2);
        float f3x = bflo(u3), f3y = bfhi(u3);
        float d0 = q2.x * f0x + q2.y * f0y;
        float d1 = q2.x * f1x + q2.y * f1y;
        float d2 = q2.x * f2x + q2.y * f2y;
        float d3 = q2.x * f3x + q2.y * f3y;
        #pragma unroll
        for (int off = 1; off <= 8; off <<= 1) {
            d0 += __shfl_xor(d0, off);
            d1 += __shfl_xor(d1, off);
            d2 += __shfl_xor(d2, off);
            d3 += __shfl_xor(d3, off);
        }
        float a0 = d0 * SC, a1 = d1 * SC, a2 = d2 * SC, a3 = d3 * SC;
        float mm = fmaxf(fmaxf(a0, a1), fmaxf(a2, a3));
        float newm = fmaxf(m, mm);
        float scale = __expf(m - newm);
        float w0 = __expf(a0 - newm), w1 = __expf(a1 - newm);
        float w2 = __expf(a2 - newm), w3 = __expf(a3 - newm);
        s  = s  * scale + ((w0 + w1) + (w2 + w3));
        ax = ax * scale + ((w0 * f0x + w1 * f1x) + (w2 * f2x + w3 * f3x));
        ay = ay * scale + ((w0 * f0y + w1 * f1y) + (w2 * f2y + w3 * f3y));
        m = newm;
    }
    for (; p < end; ++p) {
        int h = hes[p];
        unsigned int u = he_feat[(size_t)h * 64 + lane];
        float fx = bflo(u), fy = bfhi(u);
        float d = q2.x * fx + q2.y * fy;
        d += __shfl_xor(d, 1);
        d += __shfl_xor(d, 2);
        d += __shfl_xor(d, 4);
        d += __shfl_xor(d, 8);
        float a = d * SC;
        float newm = fmaxf(m, a);
        float scale = __expf(m - newm);
        float w = __expf(a - newm);
        s  = s  * scale + w;
        ax = ax * scale + w * fx;
        ay = ay * scale + w * fy;
        m = newm;
    }
    float inv = 1.f / (s + 1e-16f);
    ((float2*)node_out)[(size_t)n * 64 + lane] = make_float2(ax * inv, ay * inv);
}

// ---------------------------------------------------------------------------
extern "C" void kernel_launch(void* const* d_in, const int* in_sizes, int n_in,
                              void* d_out, int out_size, void* d_ws, size_t ws_size,
                              hipStream_t stream)
{
    const float* x        = (const float*)d_in[0];
    const int*   node_idx = (const int*)d_in[1];
    const int*   he_idx   = (const int*)d_in[2];
    const float* Wk       = (const float*)d_in[3];
    const float* bk       = (const float*)d_in[4];
    const float* Wq       = (const float*)d_in[5];
    const float* bq       = (const float*)d_in[6];
    const float* Wa       = (const float*)d_in[7];
    const float* ba       = (const float*)d_in[8];
    float*       out      = (float*)d_out;

    const int N = in_sizes[0] / D;
    const int E = in_sizes[1];

    // Workspace layout.
    float* ws      = (float*)d_ws;
    float* Kbuf    = ws;                               // N*D region (bf16 K / later f32 node_out)
    float* Qbuf    = Kbuf    + (size_t)N * D;          // N*D f32 (Q)
    float* he_feat = Qbuf    + (size_t)N * D;          // NUM_HE*D region (bf16 in half)
    unsigned short* wfrag = (unsigned short*)(he_feat + (size_t)NUM_HE * D); // 3*32768
    int*   ibase   = (int*)(wfrag + 3 * 32768);
    int*   he_ptr  = ibase;                            // NUM_HE+1
    int*   he_cnt  = he_ptr  + (NUM_HE + 1);           // NUM_HE
    int*   he_mem  = he_cnt  + NUM_HE;                 // E (node ids by he)
    int*   nd_ptr  = he_mem  + E;                      // N+1
    int*   nd_cnt  = nd_ptr  + (N + 1);                // N
    int*   nd_he   = nd_cnt  + N;                      // E (he ids by node)
    int*   partial = nd_he   + E;                      // 128
    int*   bcur    = partial + 128;                    // 1024
    uint2* staging = (uint2*)(bcur + 1024);            // E pairs (8B)

    const int gemm_grid = (N + 127) / 128;

    // W fragments (hi/lo) for all three projections
    wprep<<<(3 * 16384 + 255) / 256, 256, 0, stream>>>(Wk, Wq, Wa, wfrag);

    // Stage 1: K (bf16 out), Q (fp32 out) projections
    gemm_split<false, true><<<gemm_grid, 256, 0, stream>>>(
        x, nullptr, wfrag, wfrag + 16384, bk, Kbuf, N);
    gemm_split<false, false><<<gemm_grid, 256, 0, stream>>>(
        x, nullptr, wfrag + 32768, wfrag + 49152, bq, Qbuf, N);

    const int bin_grid = (E + BIN_CH - 1) / BIN_CH;

    // CSR by hyperedge (SHIFT=5: 625 buckets of 32 segs)
    {
        const int npb = (NUM_HE + 1023) / 1024;
        const int nb  = (NUM_HE + 31) >> 5;
        hipMemsetAsync(he_cnt, 0, sizeof(int) * NUM_HE, stream);
        hist_kernel<<<(E + 255) / 256, 256, 0, stream>>>(he_idx, he_cnt, E);
        scan_block<<<npb, 1024, 0, stream>>>(he_cnt, he_ptr, partial, NUM_HE);
        scan_partials<<<1, 128, 0, stream>>>(partial, he_ptr + NUM_HE, npb);
        scan_add<<<(NUM_HE + 255) / 256, 256, 0, stream>>>(he_ptr, partial, NUM_HE);
        init_bcur<5><<<(nb + 255) / 256, 256, 0, stream>>>(he_ptr, bcur, NUM_HE, nb);
        bin_pairs<5, 640><<<bin_grid, 256, 0, stream>>>(he_idx, node_idx, bcur, staging, E, nb);
        fill_from_bins<5><<<nb, 256, 0, stream>>>(staging, he_ptr, he_mem, NUM_HE);
    }

    // CSR by node (SHIFT=7: 782 buckets of 128 segs)
    {
        const int npb = (N + 1023) / 1024;
        const int nb  = (N + 127) >> 7;
        hipMemsetAsync(nd_cnt, 0, sizeof(int) * N, stream);
        hist_kernel<<<(E + 255) / 256, 256, 0, stream>>>(node_idx, nd_cnt, E);
        scan_block<<<npb, 1024, 0, stream>>>(nd_cnt, nd_ptr, partial, N);
        scan_partials<<<1, 128, 0, stream>>>(partial, nd_ptr + N, npb);
        scan_add<<<(N + 255) / 256, 256, 0, stream>>>(nd_ptr, partial, N);
        init_bcur<7><<<(nb + 255) / 256, 256, 0, stream>>>(nd_ptr, bcur, N, nb);
        bin_pairs<7, 800><<<bin_grid, 256, 0, stream>>>(node_idx, he_idx, bcur, staging, E, nb);
        fill_from_bins<7><<<nb, 256, 0, stream>>>(staging, nd_ptr, nd_he, N);
    }

    // Stage 2: hyperedge aggregation (bf16 gather)
    gather_he<<<(NUM_HE + 3) / 4, 256, 0, stream>>>(
        (const unsigned int*)Kbuf, he_ptr, he_mem, (unsigned int*)he_feat, NUM_HE);

    // Stages 3-5: fused attention (bf16 K dead; Kbuf region becomes f32 node_out)
    fused_attn<<<(N + 3) / 4, 256, 0, stream>>>(
        Qbuf, (const unsigned int*)he_feat, nd_ptr, nd_he, Kbuf, N);

    // Stage 6: residual folded into A-load; fp32 out
    gemm_split<true, false><<<gemm_grid, 256, 0, stream>>>(
        Kbuf, x, wfrag + 65536, wfrag + 81920, ba, out, N);
}

// Round 7
// 404.038 us; speedup vs baseline: 3.3302x; 1.0433x over previous
//
#include <hip/hip_runtime.h>
#include <math.h>

#define D 128
#define HEADS 4
#define DK 32
#define NUM_HE 20000

typedef short bf16x8 __attribute__((ext_vector_type(8)));
typedef float f32x4  __attribute__((ext_vector_type(4)));

__device__ __forceinline__ unsigned short f2bf(float f) {
    unsigned int u = __float_as_uint(f);
    u = (u + 0x7fffu + ((u >> 16) & 1u)) >> 16;
    return (unsigned short)u;
}
__device__ __forceinline__ float bf2f(unsigned short h) {
    return __uint_as_float(((unsigned int)h) << 16);
}
__device__ __forceinline__ float bflo(unsigned int u) {
    return __uint_as_float(u << 16);
}
__device__ __forceinline__ float bfhi(unsigned int u) {
    return __uint_as_float(u & 0xffff0000u);
}
__device__ __forceinline__ unsigned int packbf(float lo, float hi) {
    return (unsigned int)f2bf(lo) | ((unsigned int)f2bf(hi) << 16);
}

// ---------------------------------------------------------------------------
// W preprocessing: fragment-order Wk|Wq|Wa as bf16 hi/lo.
// ---------------------------------------------------------------------------
__global__ void wprep(const float* __restrict__ Wk, const float* __restrict__ Wq,
                      const float* __restrict__ Wa, unsigned short* __restrict__ dst)
{
    int t = blockIdx.x * blockDim.x + threadIdx.x;
    if (t >= 3 * 16384) return;
    int w = t >> 14, rem = t & 16383;
    int ks = rem >> 12, nf = (rem >> 9) & 7, lane = (rem >> 3) & 63, j = rem & 7;
    int r = ks * 32 + (lane >> 4) * 8 + j;
    int c = nf * 16 + (lane & 15);
    const float* W = (w == 0) ? Wk : (w == 1) ? Wq : Wa;
    float v = W[r * 128 + c];
    unsigned short h = f2bf(v);
    dst[(size_t)w * 32768 + rem]         = h;
    dst[(size_t)w * 32768 + 16384 + rem] = f2bf(v - bf2f(h));
}

// ---------------------------------------------------------------------------
// Split-bf16 MFMA GEMM: C[M,128] = (A (+R)) @ W + bias, W pre-fragmented.
// ---------------------------------------------------------------------------
template<bool RES, bool OUTBF>
__global__ __launch_bounds__(256) void gemm_split(
    const float* __restrict__ A, const float* __restrict__ R,
    const unsigned short* __restrict__ Bh, const unsigned short* __restrict__ Bl,
    const float* __restrict__ bias, float* __restrict__ C, int M)
{
    const int lane = threadIdx.x & 63;
    const int wv   = threadIdx.x >> 6;
    const int r0   = blockIdx.x * 128 + wv * 32;
    const int lr   = lane & 15;
    const int kg   = lane >> 4;

    f32x4 acc[2][8];
    #pragma unroll
    for (int m = 0; m < 2; ++m)
        #pragma unroll
        for (int n = 0; n < 8; ++n) acc[m][n] = (f32x4){0.f, 0.f, 0.f, 0.f};

    int row[2];
    row[0] = min(r0 + lr,      M - 1);
    row[1] = min(r0 + 16 + lr, M - 1);

    for (int ks = 0; ks < 4; ++ks) {
        bf16x8 ah[2], al[2];
        #pragma unroll
        for (int m = 0; m < 2; ++m) {
            const float* p = A + (size_t)row[m] * D + ks * 32 + kg * 8;
            float4 v0 = *(const float4*)p;
            float4 v1 = *(const float4*)(p + 4);
            float vv[8] = {v0.x, v0.y, v0.z, v0.w, v1.x, v1.y, v1.z, v1.w};
            if (RES) {
                const float* q = R + (size_t)row[m] * D + ks * 32 + kg * 8;
                float4 u0 = *(const float4*)q;
                float4 u1 = *(const float4*)(q + 4);
                vv[0] += u0.x; vv[1] += u0.y; vv[2] += u0.z; vv[3] += u0.w;
                vv[4] += u1.x; vv[5] += u1.y; vv[6] += u1.z; vv[7] += u1.w;
            }
            #pragma unroll
            for (int j = 0; j < 8; ++j) {
                unsigned short h = f2bf(vv[j]);
                ah[m][j] = (short)h;
                al[m][j] = (short)f2bf(vv[j] - bf2f(h));
            }
        }
        #pragma unroll
        for (int nf = 0; nf < 8; ++nf) {
            const int boff = ((ks * 8 + nf) * 64 + lane) * 8;
            bf16x8 bh = *(const bf16x8*)(const void*)(Bh + boff);
            bf16x8 bl = *(const bf16x8*)(const void*)(Bl + boff);
            #pragma unroll
            for (int m = 0; m < 2; ++m) {
                acc[m][nf] = __builtin_amdgcn_mfma_f32_16x16x32_bf16(ah[m], bh, acc[m][nf], 0, 0, 0);
                acc[m][nf] = __builtin_amdgcn_mfma_f32_16x16x32_bf16(ah[m], bl, acc[m][nf], 0, 0, 0);
                acc[m][nf] = __builtin_amdgcn_mfma_f32_16x16x32_bf16(al[m], bh, acc[m][nf], 0, 0, 0);
            }
        }
    }

    #pragma unroll
    for (int nf = 0; nf < 8; ++nf) {
        int col = nf * 16 + lr;
        float bv = bias[col];
        #pragma unroll
        for (int m = 0; m < 2; ++m) {
            #pragma unroll
            for (int j = 0; j < 4; ++j) {
                int gr = r0 + m * 16 + kg * 4 + j;
                if (gr < M) {
                    float v = acc[m][nf][j] + bv;
                    if (OUTBF) ((unsigned short*)C)[(size_t)gr * D + col] = f2bf(v);
                    else       C[(size_t)gr * D + col] = v;
                }
            }
        }
    }
}

// ---------------------------------------------------------------------------
// CSR construction: fused histogram -> 3-phase scan -> bucket-binned fill
// ---------------------------------------------------------------------------
__global__ void hist_both(const int* __restrict__ a, const int* __restrict__ b,
                          int* __restrict__ cnt_a, int* __restrict__ cnt_b, int E)
{
    int e = blockIdx.x * blockDim.x + threadIdx.x;
    if (e < E) {
        atomicAdd(&cnt_a[a[e]], 1);
        atomicAdd(&cnt_b[b[e]], 1);
    }
}

__global__ void scan_block(const int* __restrict__ cnt, int* __restrict__ excl,
                           int* __restrict__ partials, int n)
{
    __shared__ int wsum[16];
    const int tid  = threadIdx.x;
    const int lane = tid & 63;
    const int wid  = tid >> 6;
    int i = blockIdx.x * 1024 + tid;
    int v = (i < n) ? cnt[i] : 0;
    int x = v;
    #pragma unroll
    for (int off = 1; off < 64; off <<= 1) {
        int y = __shfl_up(x, off);
        if (lane >= off) x += y;
    }
    if (lane == 63) wsum[wid] = x;
    __syncthreads();
    if (wid == 0) {
        int wv = (lane < 16) ? wsum[lane] : 0;
        #pragma unroll
        for (int off = 1; off < 16; off <<= 1) {
            int y = __shfl_up(wv, off);
            if (lane >= off) wv += y;
        }
        if (lane < 16) wsum[lane] = wv;
    }
    __syncthreads();
    int base = (wid > 0) ? wsum[wid - 1] : 0;
    if (i < n) excl[i] = base + x - v;
    if (tid == 1023) partials[blockIdx.x] = base + x;
}

__global__ void scan_partials(int* __restrict__ partials, int* __restrict__ total, int np)
{
    __shared__ int ws[2];
    const int tid = threadIdx.x, lane = tid & 63, wid = tid >> 6;
    int v = (tid < np) ? partials[tid] : 0;
    int x = v;
    #pragma unroll
    for (int off = 1; off < 64; off <<= 1) {
        int y = __shfl_up(x, off);
        if (lane >= off) x += y;
    }
    if (lane == 63) ws[wid] = x;
    __syncthreads();
    int incl = x + ((wid == 1) ? ws[0] : 0);
    if (tid < np) partials[tid] = incl - v;
    if (tid == np - 1) *total = incl;
}

__global__ void scan_add(int* __restrict__ ptr, const int* __restrict__ partials, int n)
{
    int i = blockIdx.x * blockDim.x + threadIdx.x;
    if (i >= n) return;
    ptr[i] += partials[i >> 10];
}

template<int SHIFT>
__global__ void init_bcur(const int* __restrict__ ptr, int* __restrict__ bcur,
                          int nseg, int nb)
{
    int b = blockIdx.x * blockDim.x + threadIdx.x;
    if (b < nb) bcur[b] = ptr[min(b << SHIFT, nseg)];
}

#define BIN_CH 4096
template<int SHIFT, int MAXNB>
__global__ __launch_bounds__(256) void bin_pairs(
    const int* __restrict__ seg, const int* __restrict__ val,
    int* __restrict__ bcur, uint2* __restrict__ staging, int E, int nb)
{
    __shared__ int hist[MAXNB];
    __shared__ int base[MAXNB];
    const int tid = threadIdx.x;
    const int e0  = blockIdx.x * BIN_CH;
    for (int i = tid; i < nb; i += 256) hist[i] = 0;
    __syncthreads();
    int myseg[16], myval[16], myrank[16];
    #pragma unroll
    for (int j = 0; j < 16; ++j) {
        int e = e0 + j * 256 + tid;
        if (e < E) {
            int s = seg[e];
            myseg[j]  = s;
            myval[j]  = val[e];
            myrank[j] = atomicAdd(&hist[s >> SHIFT], 1);
        } else myseg[j] = -1;
    }
    __syncthreads();
    for (int i = tid; i < nb; i += 256) {
        int c = hist[i];
        base[i] = c ? atomicAdd(&bcur[i], c) : 0;
    }
    __syncthreads();
    #pragma unroll
    for (int j = 0; j < 16; ++j) {
        if (myseg[j] >= 0) {
            int b = myseg[j] >> SHIFT;
            staging[base[b] + myrank[j]] = make_uint2((unsigned)myseg[j], (unsigned)myval[j]);
        }
    }
}

template<int SHIFT>
__global__ __launch_bounds__(256) void fill_from_bins(
    const uint2* __restrict__ staging, const int* __restrict__ ptr,
    int* __restrict__ outv, int nseg)
{
    __shared__ int cur[1 << SHIFT];
    const int b  = blockIdx.x;
    const int s0 = b << SHIFT;
    const int s1 = min(s0 + (1 << SHIFT), nseg);
    for (int i = threadIdx.x; i < s1 - s0; i += 256) cur[i] = ptr[s0 + i];
    __syncthreads();
    const int beg = ptr[s0], end = ptr[s1];
    for (int p = beg + threadIdx.x; p < end; p += 256) {
        uint2 pv = staging[p];
        int pos = atomicAdd(&cur[(int)pv.x - s0], 1);
        outv[pos] = (int)pv.y;
    }
}

// ---------------------------------------------------------------------------
// Stage 2: he_feat[h] = sum of member K rows.
// Half-wave layout: lane = (half:1)(q:5); each half handles one member per
// step; lane q covers 4 dims (uint2 of bf16). One 64-lane load = 2 rows.
// ---------------------------------------------------------------------------
__global__ void gather_he(const uint2* __restrict__ K2,
                          const int* __restrict__ he_ptr,
                          const int* __restrict__ members,
                          uint2* __restrict__ he_feat2, int HE)
{
    int h = blockIdx.x * 4 + (threadIdx.x >> 6);
    if (h >= HE) return;
    int lane = threadIdx.x & 63;
    int half = lane >> 5;
    int q    = lane & 31;
    int beg = he_ptr[h], end = he_ptr[h + 1];
    float a0 = 0.f, a1 = 0.f, a2 = 0.f, a3 = 0.f;
    int p = beg;
    for (; p + 7 < end; p += 8) {       // 4 pairs = 8 members, 4 loads in flight
        int nA = members[p     + half];
        int nB = members[p + 2 + half];
        int nC = members[p + 4 + half];
        int nD = members[p + 6 + half];
        uint2 uA = K2[(size_t)nA * 32 + q];
        uint2 uB = K2[(size_t)nB * 32 + q];
        uint2 uC = K2[(size_t)nC * 32 + q];
        uint2 uD = K2[(size_t)nD * 32 + q];
        a0 += (bflo(uA.x) + bflo(uB.x)) + (bflo(uC.x) + bflo(uD.x));
        a1 += (bfhi(uA.x) + bfhi(uB.x)) + (bfhi(uC.x) + bfhi(uD.x));
        a2 += (bflo(uA.y) + bflo(uB.y)) + (bflo(uC.y) + bflo(uD.y));
        a3 += (bfhi(uA.y) + bfhi(uB.y)) + (bfhi(uC.y) + bfhi(uD.y));
    }
    for (; p < end; p += 2) {
        int pi = p + half;
        bool valid = pi < end;
        int nn = members[valid ? pi : beg];
        uint2 u = K2[(size_t)nn * 32 + q];
        float w = valid ? 1.f : 0.f;
        a0 += w * bflo(u.x);
        a1 += w * bfhi(u.x);
        a2 += w * bflo(u.y);
        a3 += w * bfhi(u.y);
    }
    a0 += __shfl_xor(a0, 32);
    a1 += __shfl_xor(a1, 32);
    a2 += __shfl_xor(a2, 32);
    a3 += __shfl_xor(a3, 32);
    if (half == 0)
        he_feat2[(size_t)h * 32 + q] = make_uint2(packbf(a0, a1), packbf(a2, a3));
}

// ---------------------------------------------------------------------------
// Stages 3-5 fused: per-node online softmax + weighted accumulate.
// Half-wave layout: each half processes one entry/step; lane q covers 4 dims
// of head q>>3 (8 lanes/head -> 3-step shfl reduce). Halves merged at end.
// ---------------------------------------------------------------------------
__global__ void fused_attn(const float* __restrict__ Q,
                           const uint2* __restrict__ he_feat2,
                           const int* __restrict__ node_ptr,
                           const int* __restrict__ hes,
                           float* __restrict__ node_out, int N)
{
    const float SC = 0.17677669529663687f;   // 1/sqrt(32)
    const float NEG = -1e30f;
    int n = blockIdx.x * 4 + (threadIdx.x >> 6);
    if (n >= N) return;
    int lane = threadIdx.x & 63;
    int half = lane >> 5;
    int q    = lane & 31;
    int beg = node_ptr[n], end = node_ptr[n + 1];
    float4 q4 = ((const float4*)Q)[(size_t)n * 32 + q];
    float m = NEG, s = 0.f;
    float a0 = 0.f, a1 = 0.f, a2 = 0.f, a3 = 0.f;

    int p = beg;
    for (; p + 7 < end; p += 8) {        // 4 pairs = 8 entries, 4 loads in flight
        int hA = hes[p     + half];
        int hB = hes[p + 2 + half];
        int hC = hes[p + 4 + half];
        int hD = hes[p + 6 + half];
        uint2 uA = he_feat2[(size_t)hA * 32 + q];
        uint2 uB = he_feat2[(size_t)hB * 32 + q];
        uint2 uC = he_feat2[(size_t)hC * 32 + q];
        uint2 uD = he_feat2[(size_t)hD * 32 + q];
        float fA0 = bflo(uA.x), fA1 = bfhi(uA.x), fA2 = bflo(uA.y), fA3 = bfhi(uA.y);
        float fB0 = bflo(uB.x), fB1 = bfhi(uB.x), fB2 = bflo(uB.y), fB3 = bfhi(uB.y);
        float fC0 = bflo(uC.x), fC1 = bfhi(uC.x), fC2 = bflo(uC.y), fC3 = bfhi(uC.y);
        float fD0 = bflo(uD.x), fD1 = bfhi(uD.x), fD2 = bflo(uD.y), fD3 = bfhi(uD.y);
        float dA = q4.x * fA0 + q4.y * fA1 + q4.z * fA2 + q4.w * fA3;
        float dB = q4.x * fB0 + q4.y * fB1 + q4.z * fB2 + q4.w * fB3;
        float dC = q4.x * fC0 + q4.y * fC1 + q4.z * fC2 + q4.w * fC3;
        float dD = q4.x * fD0 + q4.y * fD1 + q4.z * fD2 + q4.w * fD3;
        #pragma unroll
        for (int off = 1; off <= 4; off <<= 1) {
            dA += __shfl_xor(dA, off);
            dB += __shfl_xor(dB, off);
            dC += __shfl_xor(dC, off);
            dD += __shfl_xor(dD, off);
        }
        float aA = dA * SC, aB = dB * SC, aC = dC * SC, aD = dD * SC;
        float newm = fmaxf(m, fmaxf(fmaxf(aA, aB), fmaxf(aC, aD)));
        float scale = __expf(m - newm);
        float wA = __expf(aA - newm), wB = __expf(aB - newm);
        float wC = __expf(aC - newm), wD = __expf(aD - newm);
        s  = s  * scale + ((wA + wB) + (wC + wD));
        a0 = a0 * scale + ((wA * fA0 + wB * fB0) + (wC * fC0 + wD * fD0));
        a1 = a1 * scale + ((wA * fA1 + wB * fB1) + (wC * fC1 + wD * fD1));
        a2 = a2 * scale + ((wA * fA2 + wB * fB2) + (wC * fC2 + wD * fD2));
        a3 = a3 * scale + ((wA * fA3 + wB * fB3) + (wC * fC3 + wD * fD3));
        m = newm;
    }
    for (; p < end; p += 2) {
        int pi = p + half;
        bool valid = pi < end;
        int h = hes[valid ? pi : beg];
        uint2 u = he_feat2[(size_t)h * 32 + q];
        float f0 = bflo(u.x), f1 = bfhi(u.x), f2 = bflo(u.y), f3 = bfhi(u.y);
        float d = q4.x * f0 + q4.y * f1 + q4.z * f2 + q4.w * f3;
        d += __shfl_xor(d, 1);
        d += __shfl_xor(d, 2);
        d += __shfl_xor(d, 4);
        float a = d * SC;
        float newm = valid ? fmaxf(m, a) : m;
        float scale = __expf(m - newm);
        float w = valid ? __expf(a - newm) : 0.f;
        s  = s  * scale + w;
        a0 = a0 * scale + w * f0;
        a1 = a1 * scale + w * f1;
        a2 = a2 * scale + w * f2;
        a3 = a3 * scale + w * f3;
        m = newm;
    }
    // merge the two halves
    float mo = __shfl_xor(m, 32);
    float so = __shfl_xor(s, 32);
    float b0 = __shfl_xor(a0, 32);
    float b1 = __shfl_xor(a1, 32);
    float b2 = __shfl_xor(a2, 32);
    float b3 = __shfl_xor(a3, 32);
    float M  = fmaxf(m, mo);
    float e1 = __expf(m - M), e2 = __expf(mo - M);
    float S  = s * e1 + so * e2;
    float inv = 1.f / (S + 1e-16f);
    if (half == 0) {
        float4 o;
        o.x = (a0 * e1 + b0 * e2) * inv;
        o.y = (a1 * e1 + b1 * e2) * inv;
        o.z = (a2 * e1 + b2 * e2) * inv;
        o.w = (a3 * e1 + b3 * e2) * inv;
        ((float4*)node_out)[(size_t)n * 32 + q] = o;
    }
}

// ---------------------------------------------------------------------------
extern "C" void kernel_launch(void* const* d_in, const int* in_sizes, int n_in,
                              void* d_out, int out_size, void* d_ws, size_t ws_size,
                              hipStream_t stream)
{
    const float* x        = (const float*)d_in[0];
    const int*   node_idx = (const int*)d_in[1];
    const int*   he_idx   = (const int*)d_in[2];
    const float* Wk       = (const float*)d_in[3];
    const float* bk       = (const float*)d_in[4];
    const float* Wq       = (const float*)d_in[5];
    const float* bq       = (const float*)d_in[6];
    const float* Wa       = (const float*)d_in[7];
    const float* ba       = (const float*)d_in[8];
    float*       out      = (float*)d_out;

    const int N = in_sizes[0] / D;
    const int E = in_sizes[1];

    // Workspace layout.
    float* ws      = (float*)d_ws;
    float* Kbuf    = ws;                               // N*D region (bf16 K / later f32 node_out)
    float* Qbuf    = Kbuf    + (size_t)N * D;          // N*D f32 (Q)
    float* he_feat = Qbuf    + (size_t)N * D;          // NUM_HE*D region (bf16 in half)
    unsigned short* wfrag = (unsigned short*)(he_feat + (size_t)NUM_HE * D); // 3*32768
    int*   ibase   = (int*)(wfrag + 3 * 32768);
    int*   he_ptr  = ibase;                            // NUM_HE+1
    int*   he_cnt  = he_ptr  + (NUM_HE + 1);           // NUM_HE
    int*   he_mem  = he_cnt  + NUM_HE;                 // E (node ids by he)
    int*   nd_ptr  = he_mem  + E;                      // N+1
    int*   nd_cnt  = nd_ptr  + (N + 1);                // N
    int*   nd_he   = nd_cnt  + N;                      // E (he ids by node)
    int*   partial = nd_he   + E;                      // 128
    int*   bcur    = partial + 128;                    // 1024
    uint2* staging = (uint2*)(bcur + 1024);            // E pairs (8B)

    const int gemm_grid = (N + 127) / 128;

    // W fragments (hi/lo) for all three projections
    wprep<<<(3 * 16384 + 255) / 256, 256, 0, stream>>>(Wk, Wq, Wa, wfrag);

    // Stage 1: K (bf16 out), Q (fp32 out) projections
    gemm_split<false, true><<<gemm_grid, 256, 0, stream>>>(
        x, nullptr, wfrag, wfrag + 16384, bk, Kbuf, N);
    gemm_split<false, false><<<gemm_grid, 256, 0, stream>>>(
        x, nullptr, wfrag + 32768, wfrag + 49152, bq, Qbuf, N);

    // fused histograms for both CSRs
    hipMemsetAsync(he_cnt, 0, sizeof(int) * NUM_HE, stream);
    hipMemsetAsync(nd_cnt, 0, sizeof(int) * N, stream);
    hist_both<<<(E + 255) / 256, 256, 0, stream>>>(he_idx, node_idx, he_cnt, nd_cnt, E);

    const int bin_grid = (E + BIN_CH - 1) / BIN_CH;

    // CSR by hyperedge (SHIFT=5: 625 buckets of 32 segs)
    {
        const int npb = (NUM_HE + 1023) / 1024;
        const int nb  = (NUM_HE + 31) >> 5;
        scan_block<<<npb, 1024, 0, stream>>>(he_cnt, he_ptr, partial, NUM_HE);
        scan_partials<<<1, 128, 0, stream>>>(partial, he_ptr + NUM_HE, npb);
        scan_add<<<(NUM_HE + 255) / 256, 256, 0, stream>>>(he_ptr, partial, NUM_HE);
        init_bcur<5><<<(nb + 255) / 256, 256, 0, stream>>>(he_ptr, bcur, NUM_HE, nb);
        bin_pairs<5, 640><<<bin_grid, 256, 0, stream>>>(he_idx, node_idx, bcur, staging, E, nb);
        fill_from_bins<5><<<nb, 256, 0, stream>>>(staging, he_ptr, he_mem, NUM_HE);
    }

    // CSR by node (SHIFT=7: 782 buckets of 128 segs)
    {
        const int npb = (N + 1023) / 1024;
        const int nb  = (N + 127) >> 7;
        scan_block<<<npb, 1024, 0, stream>>>(nd_cnt, nd_ptr, partial, N);
        scan_partials<<<1, 128, 0, stream>>>(partial, nd_ptr + N, npb);
        scan_add<<<(N + 255) / 256, 256, 0, stream>>>(nd_ptr, partial, N);
        init_bcur<7><<<(nb + 255) / 256, 256, 0, stream>>>(nd_ptr, bcur, N, nb);
        bin_pairs<7, 800><<<bin_grid, 256, 0, stream>>>(node_idx, he_idx, bcur, staging, E, nb);
        fill_from_bins<7><<<nb, 256, 0, stream>>>(staging, nd_ptr, nd_he, N);
    }

    // Stage 2: hyperedge aggregation (bf16 gather, half-wave layout)
    gather_he<<<(NUM_HE + 3) / 4, 256, 0, stream>>>(
        (const uint2*)Kbuf, he_ptr, he_mem, (uint2*)he_feat, NUM_HE);

    // Stages 3-5: fused attention (bf16 K dead; Kbuf region becomes f32 node_out)
    fused_attn<<<(N + 3) / 4, 256, 0, stream>>>(
        Qbuf, (const uint2*)he_feat, nd_ptr, nd_he, Kbuf, N);

    // Stage 6: residual folded into A-load; fp32 out
    gemm_split<true, false><<<gemm_grid, 256, 0, stream>>>(
        Kbuf, x, wfrag + 65536, wfrag + 81920, ba, out, N);
}

// Round 8
// 395.965 us; speedup vs baseline: 3.3981x; 1.0204x over previous
//
#include <hip/hip_runtime.h>
#include <math.h>

#define D 128
#define HEADS 4
#define DK 32
#define NUM_HE 20000
#define NREP 8

typedef short bf16x8 __attribute__((ext_vector_type(8)));
typedef float f32x4  __attribute__((ext_vector_type(4)));

__device__ __forceinline__ unsigned short f2bf(float f) {
    unsigned int u = __float_as_uint(f);
    u = (u + 0x7fffu + ((u >> 16) & 1u)) >> 16;
    return (unsigned short)u;
}
__device__ __forceinline__ float bf2f(unsigned short h) {
    return __uint_as_float(((unsigned int)h) << 16);
}
__device__ __forceinline__ float bflo(unsigned int u) {
    return __uint_as_float(u << 16);
}
__device__ __forceinline__ float bfhi(unsigned int u) {
    return __uint_as_float(u & 0xffff0000u);
}
__device__ __forceinline__ unsigned int packbf(float lo, float hi) {
    return (unsigned int)f2bf(lo) | ((unsigned int)f2bf(hi) << 16);
}

// ---------------------------------------------------------------------------
// W preprocessing: fragment-order Wk|Wq|Wa as bf16 hi/lo.
// ---------------------------------------------------------------------------
__global__ void wprep(const float* __restrict__ Wk, const float* __restrict__ Wq,
                      const float* __restrict__ Wa, unsigned short* __restrict__ dst)
{
    int t = blockIdx.x * blockDim.x + threadIdx.x;
    if (t >= 3 * 16384) return;
    int w = t >> 14, rem = t & 16383;
    int ks = rem >> 12, nf = (rem >> 9) & 7, lane = (rem >> 3) & 63, j = rem & 7;
    int r = ks * 32 + (lane >> 4) * 8 + j;
    int c = nf * 16 + (lane & 15);
    const float* W = (w == 0) ? Wk : (w == 1) ? Wq : Wa;
    float v = W[r * 128 + c];
    unsigned short h = f2bf(v);
    dst[(size_t)w * 32768 + rem]         = h;
    dst[(size_t)w * 32768 + 16384 + rem] = f2bf(v - bf2f(h));
}

// ---------------------------------------------------------------------------
// Split-bf16 MFMA GEMM: C[M,128] = (A (+R)) @ W + bias, W pre-fragmented.
// ---------------------------------------------------------------------------
template<bool RES, bool OUTBF>
__global__ __launch_bounds__(256) void gemm_split(
    const float* __restrict__ A, const float* __restrict__ R,
    const unsigned short* __restrict__ Bh, const unsigned short* __restrict__ Bl,
    const float* __restrict__ bias, float* __restrict__ C, int M)
{
    const int lane = threadIdx.x & 63;
    const int wv   = threadIdx.x >> 6;
    const int r0   = blockIdx.x * 128 + wv * 32;
    const int lr   = lane & 15;
    const int kg   = lane >> 4;

    f32x4 acc[2][8];
    #pragma unroll
    for (int m = 0; m < 2; ++m)
        #pragma unroll
        for (int n = 0; n < 8; ++n) acc[m][n] = (f32x4){0.f, 0.f, 0.f, 0.f};

    int row[2];
    row[0] = min(r0 + lr,      M - 1);
    row[1] = min(r0 + 16 + lr, M - 1);

    for (int ks = 0; ks < 4; ++ks) {
        bf16x8 ah[2], al[2];
        #pragma unroll
        for (int m = 0; m < 2; ++m) {
            const float* p = A + (size_t)row[m] * D + ks * 32 + kg * 8;
            float4 v0 = *(const float4*)p;
            float4 v1 = *(const float4*)(p + 4);
            float vv[8] = {v0.x, v0.y, v0.z, v0.w, v1.x, v1.y, v1.z, v1.w};
            if (RES) {
                const float* q = R + (size_t)row[m] * D + ks * 32 + kg * 8;
                float4 u0 = *(const float4*)q;
                float4 u1 = *(const float4*)(q + 4);
                vv[0] += u0.x; vv[1] += u0.y; vv[2] += u0.z; vv[3] += u0.w;
                vv[4] += u1.x; vv[5] += u1.y; vv[6] += u1.z; vv[7] += u1.w;
            }
            #pragma unroll
            for (int j = 0; j < 8; ++j) {
                unsigned short h = f2bf(vv[j]);
                ah[m][j] = (short)h;
                al[m][j] = (short)f2bf(vv[j] - bf2f(h));
            }
        }
        #pragma unroll
        for (int nf = 0; nf < 8; ++nf) {
            const int boff = ((ks * 8 + nf) * 64 + lane) * 8;
            bf16x8 bh = *(const bf16x8*)(const void*)(Bh + boff);
            bf16x8 bl = *(const bf16x8*)(const void*)(Bl + boff);
            #pragma unroll
            for (int m = 0; m < 2; ++m) {
                acc[m][nf] = __builtin_amdgcn_mfma_f32_16x16x32_bf16(ah[m], bh, acc[m][nf], 0, 0, 0);
                acc[m][nf] = __builtin_amdgcn_mfma_f32_16x16x32_bf16(ah[m], bl, acc[m][nf], 0, 0, 0);
                acc[m][nf] = __builtin_amdgcn_mfma_f32_16x16x32_bf16(al[m], bh, acc[m][nf], 0, 0, 0);
            }
        }
    }

    #pragma unroll
    for (int nf = 0; nf < 8; ++nf) {
        int col = nf * 16 + lr;
        float bv = bias[col];
        #pragma unroll
        for (int m = 0; m < 2; ++m) {
            #pragma unroll
            for (int j = 0; j < 4; ++j) {
                int gr = r0 + m * 16 + kg * 4 + j;
                if (gr < M) {
                    float v = acc[m][nf][j] + bv;
                    if (OUTBF) ((unsigned short*)C)[(size_t)gr * D + col] = f2bf(v);
                    else       C[(size_t)gr * D + col] = v;
                }
            }
        }
    }
}

// ---------------------------------------------------------------------------
// CSR construction: XCD-privatized histogram -> reduce -> scan -> binned fill
// ---------------------------------------------------------------------------
// Each replica r = blockIdx&7 gets its own [he: NUM_HE][nd: N] counter array;
// blocks dispatch round-robin across XCDs, so replica lines stay in one
// XCD's L2 (no cross-XCD ownership ping-pong).
__global__ void hist_rep(const int* __restrict__ he, const int* __restrict__ nd,
                         int* __restrict__ rep, int E, int N)
{
    const int stride = NUM_HE + N;
    int* myrep = rep + (size_t)(blockIdx.x & (NREP - 1)) * stride;
    int e = blockIdx.x * blockDim.x + threadIdx.x;
    if (e < E) {
        atomicAdd(&myrep[he[e]], 1);
        atomicAdd(&myrep[NUM_HE + nd[e]], 1);
    }
}

// cnt[i] = sum over replicas; i in [0, NUM_HE+N); he_cnt then nd_cnt.
__global__ void reduce_rep(const int* __restrict__ rep,
                           int* __restrict__ he_cnt, int* __restrict__ nd_cnt, int N)
{
    const int stride = NUM_HE + N;
    int i = blockIdx.x * blockDim.x + threadIdx.x;
    if (i >= stride) return;
    int s = 0;
    #pragma unroll
    for (int r = 0; r < NREP; ++r) s += rep[(size_t)r * stride + i];
    if (i < NUM_HE) he_cnt[i] = s;
    else            nd_cnt[i - NUM_HE] = s;
}

__global__ void scan_block(const int* __restrict__ cnt, int* __restrict__ excl,
                           int* __restrict__ partials, int n)
{
    __shared__ int wsum[16];
    const int tid  = threadIdx.x;
    const int lane = tid & 63;
    const int wid  = tid >> 6;
    int i = blockIdx.x * 1024 + tid;
    int v = (i < n) ? cnt[i] : 0;
    int x = v;
    #pragma unroll
    for (int off = 1; off < 64; off <<= 1) {
        int y = __shfl_up(x, off);
        if (lane >= off) x += y;
    }
    if (lane == 63) wsum[wid] = x;
    __syncthreads();
    if (wid == 0) {
        int wv = (lane < 16) ? wsum[lane] : 0;
        #pragma unroll
        for (int off = 1; off < 16; off <<= 1) {
            int y = __shfl_up(wv, off);
            if (lane >= off) wv += y;
        }
        if (lane < 16) wsum[lane] = wv;
    }
    __syncthreads();
    int base = (wid > 0) ? wsum[wid - 1] : 0;
    if (i < n) excl[i] = base + x - v;
    if (tid == 1023) partials[blockIdx.x] = base + x;
}

__global__ void scan_partials(int* __restrict__ partials, int* __restrict__ total, int np)
{
    __shared__ int ws[2];
    const int tid = threadIdx.x, lane = tid & 63, wid = tid >> 6;
    int v = (tid < np) ? partials[tid] : 0;
    int x = v;
    #pragma unroll
    for (int off = 1; off < 64; off <<= 1) {
        int y = __shfl_up(x, off);
        if (lane >= off) x += y;
    }
    if (lane == 63) ws[wid] = x;
    __syncthreads();
    int incl = x + ((wid == 1) ? ws[0] : 0);
    if (tid < np) partials[tid] = incl - v;
    if (tid == np - 1) *total = incl;
}

__global__ void scan_add(int* __restrict__ ptr, const int* __restrict__ partials, int n)
{
    int i = blockIdx.x * blockDim.x + threadIdx.x;
    if (i >= n) return;
    ptr[i] += partials[i >> 10];
}

template<int SHIFT>
__global__ void init_bcur(const int* __restrict__ ptr, int* __restrict__ bcur,
                          int nseg, int nb)
{
    int b = blockIdx.x * blockDim.x + threadIdx.x;
    if (b < nb) bcur[b] = ptr[min(b << SHIFT, nseg)];
}

#define BIN_CH 4096
template<int SHIFT, int MAXNB>
__global__ __launch_bounds__(256) void bin_pairs(
    const int* __restrict__ seg, const int* __restrict__ val,
    int* __restrict__ bcur, uint2* __restrict__ staging, int E, int nb)
{
    __shared__ int hist[MAXNB];
    __shared__ int base[MAXNB];
    const int tid = threadIdx.x;
    const int e0  = blockIdx.x * BIN_CH;
    for (int i = tid; i < nb; i += 256) hist[i] = 0;
    __syncthreads();
    int myseg[16], myval[16], myrank[16];
    #pragma unroll
    for (int j = 0; j < 16; ++j) {
        int e = e0 + j * 256 + tid;
        if (e < E) {
            int s = seg[e];
            myseg[j]  = s;
            myval[j]  = val[e];
            myrank[j] = atomicAdd(&hist[s >> SHIFT], 1);
        } else myseg[j] = -1;
    }
    __syncthreads();
    for (int i = tid; i < nb; i += 256) {
        int c = hist[i];
        base[i] = c ? atomicAdd(&bcur[i], c) : 0;
    }
    __syncthreads();
    #pragma unroll
    for (int j = 0; j < 16; ++j) {
        if (myseg[j] >= 0) {
            int b = myseg[j] >> SHIFT;
            staging[base[b] + myrank[j]] = make_uint2((unsigned)myseg[j], (unsigned)myval[j]);
        }
    }
}

template<int SHIFT>
__global__ __launch_bounds__(256) void fill_from_bins(
    const uint2* __restrict__ staging, const int* __restrict__ ptr,
    int* __restrict__ outv, int nseg)
{
    __shared__ int cur[1 << SHIFT];
    const int b  = blockIdx.x;
    const int s0 = b << SHIFT;
    const int s1 = min(s0 + (1 << SHIFT), nseg);
    for (int i = threadIdx.x; i < s1 - s0; i += 256) cur[i] = ptr[s0 + i];
    __syncthreads();
    const int beg = ptr[s0], end = ptr[s1];
    for (int p = beg + threadIdx.x; p < end; p += 256) {
        uint2 pv = staging[p];
        int pos = atomicAdd(&cur[(int)pv.x - s0], 1);
        outv[pos] = (int)pv.y;
    }
}

// ---------------------------------------------------------------------------
// Stage 2: he_feat[h] = sum of member K rows (half-wave layout).
// ---------------------------------------------------------------------------
__global__ void gather_he(const uint2* __restrict__ K2,
                          const int* __restrict__ he_ptr,
                          const int* __restrict__ members,
                          uint2* __restrict__ he_feat2, int HE)
{
    int h = blockIdx.x * 4 + (threadIdx.x >> 6);
    if (h >= HE) return;
    int lane = threadIdx.x & 63;
    int half = lane >> 5;
    int q    = lane & 31;
    int beg = he_ptr[h], end = he_ptr[h + 1];
    float a0 = 0.f, a1 = 0.f, a2 = 0.f, a3 = 0.f;
    int p = beg;
    for (; p + 7 < end; p += 8) {
        int nA = members[p     + half];
        int nB = members[p + 2 + half];
        int nC = members[p + 4 + half];
        int nD = members[p + 6 + half];
        uint2 uA = K2[(size_t)nA * 32 + q];
        uint2 uB = K2[(size_t)nB * 32 + q];
        uint2 uC = K2[(size_t)nC * 32 + q];
        uint2 uD = K2[(size_t)nD * 32 + q];
        a0 += (bflo(uA.x) + bflo(uB.x)) + (bflo(uC.x) + bflo(uD.x));
        a1 += (bfhi(uA.x) + bfhi(uB.x)) + (bfhi(uC.x) + bfhi(uD.x));
        a2 += (bflo(uA.y) + bflo(uB.y)) + (bflo(uC.y) + bflo(uD.y));
        a3 += (bfhi(uA.y) + bfhi(uB.y)) + (bfhi(uC.y) + bfhi(uD.y));
    }
    for (; p < end; p += 2) {
        int pi = p + half;
        bool valid = pi < end;
        int nn = members[valid ? pi : beg];
        uint2 u = K2[(size_t)nn * 32 + q];
        float w = valid ? 1.f : 0.f;
        a0 += w * bflo(u.x);
        a1 += w * bfhi(u.x);
        a2 += w * bflo(u.y);
        a3 += w * bfhi(u.y);
    }
    a0 += __shfl_xor(a0, 32);
    a1 += __shfl_xor(a1, 32);
    a2 += __shfl_xor(a2, 32);
    a3 += __shfl_xor(a3, 32);
    if (half == 0)
        he_feat2[(size_t)h * 32 + q] = make_uint2(packbf(a0, a1), packbf(a2, a3));
}

// ---------------------------------------------------------------------------
// Stages 3-5 fused: per-node online softmax + weighted accumulate (half-wave).
// ---------------------------------------------------------------------------
__global__ void fused_attn(const float* __restrict__ Q,
                           const uint2* __restrict__ he_feat2,
                           const int* __restrict__ node_ptr,
                           const int* __restrict__ hes,
                           float* __restrict__ node_out, int N)
{
    const float SC = 0.17677669529663687f;   // 1/sqrt(32)
    const float NEG = -1e30f;
    int n = blockIdx.x * 4 + (threadIdx.x >> 6);
    if (n >= N) return;
    int lane = threadIdx.x & 63;
    int half = lane >> 5;
    int q    = lane & 31;
    int beg = node_ptr[n], end = node_ptr[n + 1];
    float4 q4 = ((const float4*)Q)[(size_t)n * 32 + q];
    float m = NEG, s = 0.f;
    float a0 = 0.f, a1 = 0.f, a2 = 0.f, a3 = 0.f;

    int p = beg;
    for (; p + 7 < end; p += 8) {
        int hA = hes[p     + half];
        int hB = hes[p + 2 + half];
        int hC = hes[p + 4 + half];
        int hD = hes[p + 6 + half];
        uint2 uA = he_feat2[(size_t)hA * 32 + q];
        uint2 uB = he_feat2[(size_t)hB * 32 + q];
        uint2 uC = he_feat2[(size_t)hC * 32 + q];
        uint2 uD = he_feat2[(size_t)hD * 32 + q];
        float fA0 = bflo(uA.x), fA1 = bfhi(uA.x), fA2 = bflo(uA.y), fA3 = bfhi(uA.y);
        float fB0 = bflo(uB.x), fB1 = bfhi(uB.x), fB2 = bflo(uB.y), fB3 = bfhi(uB.y);
        float fC0 = bflo(uC.x), fC1 = bfhi(uC.x), fC2 = bflo(uC.y), fC3 = bfhi(uC.y);
        float fD0 = bflo(uD.x), fD1 = bfhi(uD.x), fD2 = bflo(uD.y), fD3 = bfhi(uD.y);
        float dA = q4.x * fA0 + q4.y * fA1 + q4.z * fA2 + q4.w * fA3;
        float dB = q4.x * fB0 + q4.y * fB1 + q4.z * fB2 + q4.w * fB3;
        float dC = q4.x * fC0 + q4.y * fC1 + q4.z * fC2 + q4.w * fC3;
        float dD = q4.x * fD0 + q4.y * fD1 + q4.z * fD2 + q4.w * fD3;
        #pragma unroll
        for (int off = 1; off <= 4; off <<= 1) {
            dA += __shfl_xor(dA, off);
            dB += __shfl_xor(dB, off);
            dC += __shfl_xor(dC, off);
            dD += __shfl_xor(dD, off);
        }
        float aA = dA * SC, aB = dB * SC, aC = dC * SC, aD = dD * SC;
        float newm = fmaxf(m, fmaxf(fmaxf(aA, aB), fmaxf(aC, aD)));
        float scale = __expf(m - newm);
        float wA = __expf(aA - newm), wB = __expf(aB - newm);
        float wC = __expf(aC - newm), wD = __expf(aD - newm);
        s  = s  * scale + ((wA + wB) + (wC + wD));
        a0 = a0 * scale + ((wA * fA0 + wB * fB0) + (wC * fC0 + wD * fD0));
        a1 = a1 * scale + ((wA * fA1 + wB * fB1) + (wC * fC1 + wD * fD1));
        a2 = a2 * scale + ((wA * fA2 + wB * fB2) + (wC * fC2 + wD * fD2));
        a3 = a3 * scale + ((wA * fA3 + wB * fB3) + (wC * fC3 + wD * fD3));
        m = newm;
    }
    for (; p < end; p += 2) {
        int pi = p + half;
        bool valid = pi < end;
        int h = hes[valid ? pi : beg];
        uint2 u = he_feat2[(size_t)h * 32 + q];
        float f0 = bflo(u.x), f1 = bfhi(u.x), f2 = bflo(u.y), f3 = bfhi(u.y);
        float d = q4.x * f0 + q4.y * f1 + q4.z * f2 + q4.w * f3;
        d += __shfl_xor(d, 1);
        d += __shfl_xor(d, 2);
        d += __shfl_xor(d, 4);
        float a = d * SC;
        float newm = valid ? fmaxf(m, a) : m;
        float scale = __expf(m - newm);
        float w = valid ? __expf(a - newm) : 0.f;
        s  = s  * scale + w;
        a0 = a0 * scale + w * f0;
        a1 = a1 * scale + w * f1;
        a2 = a2 * scale + w * f2;
        a3 = a3 * scale + w * f3;
        m = newm;
    }
    float mo = __shfl_xor(m, 32);
    float so = __shfl_xor(s, 32);
    float b0 = __shfl_xor(a0, 32);
    float b1 = __shfl_xor(a1, 32);
    float b2 = __shfl_xor(a2, 32);
    float b3 = __shfl_xor(a3, 32);
    float M  = fmaxf(m, mo);
    float e1 = __expf(m - M), e2 = __expf(mo - M);
    float S  = s * e1 + so * e2;
    float inv = 1.f / (S + 1e-16f);
    if (half == 0) {
        float4 o;
        o.x = (a0 * e1 + b0 * e2) * inv;
        o.y = (a1 * e1 + b1 * e2) * inv;
        o.z = (a2 * e1 + b2 * e2) * inv;
        o.w = (a3 * e1 + b3 * e2) * inv;
        ((float4*)node_out)[(size_t)n * 32 + q] = o;
    }
}

// ---------------------------------------------------------------------------
extern "C" void kernel_launch(void* const* d_in, const int* in_sizes, int n_in,
                              void* d_out, int out_size, void* d_ws, size_t ws_size,
                              hipStream_t stream)
{
    const float* x        = (const float*)d_in[0];
    const int*   node_idx = (const int*)d_in[1];
    const int*   he_idx   = (const int*)d_in[2];
    const float* Wk       = (const float*)d_in[3];
    const float* bk       = (const float*)d_in[4];
    const float* Wq       = (const float*)d_in[5];
    const float* bq       = (const float*)d_in[6];
    const float* Wa       = (const float*)d_in[7];
    const float* ba       = (const float*)d_in[8];
    float*       out      = (float*)d_out;

    const int N = in_sizes[0] / D;
    const int E = in_sizes[1];

    // Workspace layout.
    float* ws      = (float*)d_ws;
    float* Kbuf    = ws;                               // N*D region (bf16 K / later f32 node_out)
    float* Qbuf    = Kbuf    + (size_t)N * D;          // N*D f32 (Q)
    float* he_feat = Qbuf    + (size_t)N * D;          // NUM_HE*D region (bf16 in half)
    unsigned short* wfrag = (unsigned short*)(he_feat + (size_t)NUM_HE * D); // 3*32768
    int*   ibase   = (int*)(wfrag + 3 * 32768);
    int*   he_ptr  = ibase;                            // NUM_HE+1
    int*   he_cnt  = he_ptr  + (NUM_HE + 1);           // NUM_HE
    int*   he_mem  = he_cnt  + NUM_HE;                 // E (node ids by he)
    int*   nd_ptr  = he_mem  + E;                      // N+1
    int*   nd_cnt  = nd_ptr  + (N + 1);                // N
    int*   nd_he   = nd_cnt  + N;                      // E (he ids by node)
    int*   partial = nd_he   + E;                      // 128
    int*   bcur    = partial + 128;                    // 1024
    int*   rep     = bcur    + 1024;                   // NREP*(NUM_HE+N)
    uint2* staging = (uint2*)(rep + (size_t)NREP * (NUM_HE + N)); // E pairs

    const int gemm_grid = (N + 127) / 128;

    // W fragments (hi/lo) for all three projections
    wprep<<<(3 * 16384 + 255) / 256, 256, 0, stream>>>(Wk, Wq, Wa, wfrag);

    // Stage 1: K (bf16 out), Q (fp32 out) projections
    gemm_split<false, true><<<gemm_grid, 256, 0, stream>>>(
        x, nullptr, wfrag, wfrag + 16384, bk, Kbuf, N);
    gemm_split<false, false><<<gemm_grid, 256, 0, stream>>>(
        x, nullptr, wfrag + 32768, wfrag + 49152, bq, Qbuf, N);

    // XCD-privatized histograms for both CSRs
    hipMemsetAsync(rep, 0, sizeof(int) * (size_t)NREP * (NUM_HE + N), stream);
    hist_rep<<<(E + 255) / 256, 256, 0, stream>>>(he_idx, node_idx, rep, E, N);
    reduce_rep<<<(NUM_HE + N + 255) / 256, 256, 0, stream>>>(rep, he_cnt, nd_cnt, N);

    const int bin_grid = (E + BIN_CH - 1) / BIN_CH;

    // CSR by hyperedge (SHIFT=5: 625 buckets of 32 segs)
    {
        const int npb = (NUM_HE + 1023) / 1024;
        const int nb  = (NUM_HE + 31) >> 5;
        scan_block<<<npb, 1024, 0, stream>>>(he_cnt, he_ptr, partial, NUM_HE);
        scan_partials<<<1, 128, 0, stream>>>(partial, he_ptr + NUM_HE, npb);
        scan_add<<<(NUM_HE + 255) / 256, 256, 0, stream>>>(he_ptr, partial, NUM_HE);
        init_bcur<5><<<(nb + 255) / 256, 256, 0, stream>>>(he_ptr, bcur, NUM_HE, nb);
        bin_pairs<5, 640><<<bin_grid, 256, 0, stream>>>(he_idx, node_idx, bcur, staging, E, nb);
        fill_from_bins<5><<<nb, 256, 0, stream>>>(staging, he_ptr, he_mem, NUM_HE);
    }

    // CSR by node (SHIFT=7: 782 buckets of 128 segs)
    {
        const int npb = (N + 1023) / 1024;
        const int nb  = (N + 127) >> 7;
        scan_block<<<npb, 1024, 0, stream>>>(nd_cnt, nd_ptr, partial, N);
        scan_partials<<<1, 128, 0, stream>>>(partial, nd_ptr + N, npb);
        scan_add<<<(N + 255) / 256, 256, 0, stream>>>(nd_ptr, partial, N);
        init_bcur<7><<<(nb + 255) / 256, 256, 0, stream>>>(nd_ptr, bcur, N, nb);
        bin_pairs<7, 800><<<bin_grid, 256, 0, stream>>>(node_idx, he_idx, bcur, staging, E, nb);
        fill_from_bins<7><<<nb, 256, 0, stream>>>(staging, nd_ptr, nd_he, N);
    }

    // Stage 2: hyperedge aggregation (bf16 gather, half-wave layout)
    gather_he<<<(NUM_HE + 3) / 4, 256, 0, stream>>>(
        (const uint2*)Kbuf, he_ptr, he_mem, (uint2*)he_feat, NUM_HE);

    // Stages 3-5: fused attention (bf16 K dead; Kbuf region becomes f32 node_out)
    fused_attn<<<(N + 3) / 4, 256, 0, stream>>>(
        Qbuf, (const uint2*)he_feat, nd_ptr, nd_he, Kbuf, N);

    // Stage 6: residual folded into A-load; fp32 out
    gemm_split<true, false><<<gemm_grid, 256, 0, stream>>>(
        Kbuf, x, wfrag + 65536, wfrag + 81920, ba, out, N);
}

// Round 9
// 324.884 us; speedup vs baseline: 4.1416x; 1.2188x over previous
//
#include <hip/hip_runtime.h>
#include <math.h>

#define D 128
#define HEADS 4
#define DK 32
#define NUM_HE 20000
#define BIN_CH 4096

typedef short bf16x8 __attribute__((ext_vector_type(8)));
typedef float f32x4  __attribute__((ext_vector_type(4)));

__device__ __forceinline__ unsigned short f2bf(float f) {
    unsigned int u = __float_as_uint(f);
    u = (u + 0x7fffu + ((u >> 16) & 1u)) >> 16;
    return (unsigned short)u;
}
__device__ __forceinline__ float bf2f(unsigned short h) {
    return __uint_as_float(((unsigned int)h) << 16);
}
__device__ __forceinline__ float bflo(unsigned int u) {
    return __uint_as_float(u << 16);
}
__device__ __forceinline__ float bfhi(unsigned int u) {
    return __uint_as_float(u & 0xffff0000u);
}
__device__ __forceinline__ unsigned int packbf(float lo, float hi) {
    return (unsigned int)f2bf(lo) | ((unsigned int)f2bf(hi) << 16);
}

// ---------------------------------------------------------------------------
// W preprocessing: fragment-order Wk|Wq|Wa as bf16 hi/lo.
// ---------------------------------------------------------------------------
__global__ void wprep(const float* __restrict__ Wk, const float* __restrict__ Wq,
                      const float* __restrict__ Wa, unsigned short* __restrict__ dst)
{
    int t = blockIdx.x * blockDim.x + threadIdx.x;
    if (t >= 3 * 16384) return;
    int w = t >> 14, rem = t & 16383;
    int ks = rem >> 12, nf = (rem >> 9) & 7, lane = (rem >> 3) & 63, j = rem & 7;
    int r = ks * 32 + (lane >> 4) * 8 + j;
    int c = nf * 16 + (lane & 15);
    const float* W = (w == 0) ? Wk : (w == 1) ? Wq : Wa;
    float v = W[r * 128 + c];
    unsigned short h = f2bf(v);
    dst[(size_t)w * 32768 + rem]         = h;
    dst[(size_t)w * 32768 + 16384 + rem] = f2bf(v - bf2f(h));
}

// ---------------------------------------------------------------------------
// Split-bf16 MFMA GEMM: C[M,128] = (A (+R)) @ W + bias, W pre-fragmented.
// ---------------------------------------------------------------------------
template<bool RES, bool OUTBF>
__global__ __launch_bounds__(256) void gemm_split(
    const float* __restrict__ A, const float* __restrict__ R,
    const unsigned short* __restrict__ Bh, const unsigned short* __restrict__ Bl,
    const float* __restrict__ bias, float* __restrict__ C, int M)
{
    const int lane = threadIdx.x & 63;
    const int wv   = threadIdx.x >> 6;
    const int r0   = blockIdx.x * 128 + wv * 32;
    const int lr   = lane & 15;
    const int kg   = lane >> 4;

    f32x4 acc[2][8];
    #pragma unroll
    for (int m = 0; m < 2; ++m)
        #pragma unroll
        for (int n = 0; n < 8; ++n) acc[m][n] = (f32x4){0.f, 0.f, 0.f, 0.f};

    int row[2];
    row[0] = min(r0 + lr,      M - 1);
    row[1] = min(r0 + 16 + lr, M - 1);

    for (int ks = 0; ks < 4; ++ks) {
        bf16x8 ah[2], al[2];
        #pragma unroll
        for (int m = 0; m < 2; ++m) {
            const float* p = A + (size_t)row[m] * D + ks * 32 + kg * 8;
            float4 v0 = *(const float4*)p;
            float4 v1 = *(const float4*)(p + 4);
            float vv[8] = {v0.x, v0.y, v0.z, v0.w, v1.x, v1.y, v1.z, v1.w};
            if (RES) {
                const float* q = R + (size_t)row[m] * D + ks * 32 + kg * 8;
                float4 u0 = *(const float4*)q;
                float4 u1 = *(const float4*)(q + 4);
                vv[0] += u0.x; vv[1] += u0.y; vv[2] += u0.z; vv[3] += u0.w;
                vv[4] += u1.x; vv[5] += u1.y; vv[6] += u1.z; vv[7] += u1.w;
            }
            #pragma unroll
            for (int j = 0; j < 8; ++j) {
                unsigned short h = f2bf(vv[j]);
                ah[m][j] = (short)h;
                al[m][j] = (short)f2bf(vv[j] - bf2f(h));
            }
        }
        #pragma unroll
        for (int nf = 0; nf < 8; ++nf) {
            const int boff = ((ks * 8 + nf) * 64 + lane) * 8;
            bf16x8 bh = *(const bf16x8*)(const void*)(Bh + boff);
            bf16x8 bl = *(const bf16x8*)(const void*)(Bl + boff);
            #pragma unroll
            for (int m = 0; m < 2; ++m) {
                acc[m][nf] = __builtin_amdgcn_mfma_f32_16x16x32_bf16(ah[m], bh, acc[m][nf], 0, 0, 0);
                acc[m][nf] = __builtin_amdgcn_mfma_f32_16x16x32_bf16(ah[m], bl, acc[m][nf], 0, 0, 0);
                acc[m][nf] = __builtin_amdgcn_mfma_f32_16x16x32_bf16(al[m], bh, acc[m][nf], 0, 0, 0);
            }
        }
    }

    #pragma unroll
    for (int nf = 0; nf < 8; ++nf) {
        int col = nf * 16 + lr;
        float bv = bias[col];
        #pragma unroll
        for (int m = 0; m < 2; ++m) {
            #pragma unroll
            for (int j = 0; j < 4; ++j) {
                int gr = r0 + m * 16 + kg * 4 + j;
                if (gr < M) {
                    float v = acc[m][nf][j] + bv;
                    if (OUTBF) ((unsigned short*)C)[(size_t)gr * D + col] = f2bf(v);
                    else       C[(size_t)gr * D + col] = v;
                }
            }
        }
    }
}

// ---------------------------------------------------------------------------
// CSR construction with ZERO global atomics:
//   stage_pairs: per-block bucket-grouped staging + dense counts/boffs
//   bucket_tot : bucket totals (wave per bucket)
//   bucket_scan: exclusive scan of bucket totals -> bbase; ptr sentinel
//   fill_csr   : per bucket, local count+scan -> ptr slice + dense values
// ---------------------------------------------------------------------------
template<int SHIFT, int MAXNB>
__global__ __launch_bounds__(256) void stage_pairs(
    const int* __restrict__ seg, const int* __restrict__ val,
    int* __restrict__ counts, int* __restrict__ boffs,
    uint2* __restrict__ staging, int E, int nb)
{
    __shared__ int hist[MAXNB];
    __shared__ int offs[MAXNB];
    __shared__ int wtot[4];
    const int tid  = threadIdx.x;
    const int lane = tid & 63;
    const int wid  = tid >> 6;
    const int e0   = blockIdx.x * BIN_CH;

    for (int i = tid; i < nb; i += 256) hist[i] = 0;
    __syncthreads();

    int myseg[16], myval[16], myrank[16];
    #pragma unroll
    for (int j = 0; j < 16; ++j) {
        int e = e0 + j * 256 + tid;
        if (e < E) {
            int s = seg[e];
            myseg[j]  = s;
            myval[j]  = val[e];
            myrank[j] = atomicAdd(&hist[s >> SHIFT], 1);
        } else myseg[j] = -1;
    }
    __syncthreads();

    // exclusive scan hist -> offs (VPT=4 covers nb <= 1024)
    const int i0 = tid * 4;
    int v0 = (i0 + 0 < nb) ? hist[i0 + 0] : 0;
    int v1 = (i0 + 1 < nb) ? hist[i0 + 1] : 0;
    int v2 = (i0 + 2 < nb) ? hist[i0 + 2] : 0;
    int v3 = (i0 + 3 < nb) ? hist[i0 + 3] : 0;
    int tsum = v0 + v1 + v2 + v3;
    int x = tsum;
    #pragma unroll
    for (int off = 1; off < 64; off <<= 1) {
        int y = __shfl_up(x, off);
        if (lane >= off) x += y;
    }
    if (lane == 63) wtot[wid] = x;
    __syncthreads();
    if (tid == 0) {
        int r = 0;
        #pragma unroll
        for (int w = 0; w < 4; ++w) { int c = wtot[w]; wtot[w] = r; r += c; }
    }
    __syncthreads();
    int base = wtot[wid] + x - tsum;
    if (i0 + 0 < nb) offs[i0 + 0] = base; base += v0;
    if (i0 + 1 < nb) offs[i0 + 1] = base; base += v1;
    if (i0 + 2 < nb) offs[i0 + 2] = base; base += v2;
    if (i0 + 3 < nb) offs[i0 + 3] = base;
    __syncthreads();

    for (int i = tid; i < nb; i += 256) {
        counts[(size_t)blockIdx.x * nb + i] = hist[i];
        boffs [(size_t)blockIdx.x * nb + i] = offs[i];
    }
    #pragma unroll
    for (int j = 0; j < 16; ++j) {
        if (myseg[j] >= 0) {
            int b = myseg[j] >> SHIFT;
            staging[e0 + offs[b] + myrank[j]] =
                make_uint2((unsigned)myseg[j], (unsigned)myval[j]);
        }
    }
}

__global__ void bucket_tot(const int* __restrict__ counts, int* __restrict__ btot,
                           int nb, int nblk)
{
    int k = blockIdx.x * 4 + (threadIdx.x >> 6);
    if (k >= nb) return;
    int lane = threadIdx.x & 63;
    int s = 0;
    for (int b = lane; b < nblk; b += 64) s += counts[(size_t)b * nb + k];
    #pragma unroll
    for (int off = 1; off < 64; off <<= 1) s += __shfl_xor(s, off);
    if (lane == 0) btot[k] = s;
}

__global__ void bucket_scan(const int* __restrict__ btot, int* __restrict__ bbase,
                            int* __restrict__ ptr, int nseg, int nb, int Etot)
{
    __shared__ int wsum[16];
    const int tid = threadIdx.x, lane = tid & 63, wid = tid >> 6;
    int v = (tid < nb) ? btot[tid] : 0;
    int x = v;
    #pragma unroll
    for (int off = 1; off < 64; off <<= 1) {
        int y = __shfl_up(x, off);
        if (lane >= off) x += y;
    }
    if (lane == 63) wsum[wid] = x;
    __syncthreads();
    if (wid == 0) {
        int wv = (lane < 16) ? wsum[lane] : 0;
        #pragma unroll
        for (int off = 1; off < 16; off <<= 1) {
            int y = __shfl_up(wv, off);
            if (lane >= off) wv += y;
        }
        if (lane < 16) wsum[lane] = wv;
    }
    __syncthreads();
    int base = (wid > 0) ? wsum[wid - 1] : 0;
    if (tid < nb) bbase[tid] = base + x - v;
    if (tid == 0) ptr[nseg] = Etot;
}

template<int SHIFT>
__global__ __launch_bounds__(256) void fill_csr(
    const uint2* __restrict__ staging, const int* __restrict__ counts,
    const int* __restrict__ boffs, const int* __restrict__ bbase,
    int* __restrict__ ptr, int* __restrict__ outv,
    int nseg, int nb, int nblk)
{
    __shared__ int cur[1 << SHIFT];
    const int tid = threadIdx.x;
    const int k   = blockIdx.x;
    const int s0  = k << SHIFT;
    const int NS  = min(1 << SHIFT, nseg - s0);
    for (int i = tid; i < NS; i += 256) cur[i] = 0;
    __syncthreads();
    // pass 1: per-seg counts within bucket
    for (int b = tid; b < nblk; b += 256) {
        int c   = counts[(size_t)b * nb + k];
        int off = b * BIN_CH + boffs[(size_t)b * nb + k];
        for (int i = 0; i < c; ++i) {
            int s = (int)staging[off + i].x;
            atomicAdd(&cur[s - s0], 1);
        }
    }
    __syncthreads();
    if (tid == 0) {
        int run = bbase[k];
        for (int i = 0; i < NS; ++i) {
            int c = cur[i];
            cur[i] = run;
            ptr[s0 + i] = run;
            run += c;
        }
    }
    __syncthreads();
    // pass 2: scatter values densely into this bucket's CSR slice
    for (int b = tid; b < nblk; b += 256) {
        int c   = counts[(size_t)b * nb + k];
        int off = b * BIN_CH + boffs[(size_t)b * nb + k];
        for (int i = 0; i < c; ++i) {
            uint2 pv = staging[off + i];
            int pos = atomicAdd(&cur[(int)pv.x - s0], 1);
            outv[pos] = (int)pv.y;
        }
    }
}

// ---------------------------------------------------------------------------
// Stage 2: he_feat[h] = sum of member K rows (half-wave layout).
// ---------------------------------------------------------------------------
__global__ void gather_he(const uint2* __restrict__ K2,
                          const int* __restrict__ he_ptr,
                          const int* __restrict__ members,
                          uint2* __restrict__ he_feat2, int HE)
{
    int h = blockIdx.x * 4 + (threadIdx.x >> 6);
    if (h >= HE) return;
    int lane = threadIdx.x & 63;
    int half = lane >> 5;
    int q    = lane & 31;
    int beg = he_ptr[h], end = he_ptr[h + 1];
    float a0 = 0.f, a1 = 0.f, a2 = 0.f, a3 = 0.f;
    int p = beg;
    for (; p + 7 < end; p += 8) {
        int nA = members[p     + half];
        int nB = members[p + 2 + half];
        int nC = members[p + 4 + half];
        int nD = members[p + 6 + half];
        uint2 uA = K2[(size_t)nA * 32 + q];
        uint2 uB = K2[(size_t)nB * 32 + q];
        uint2 uC = K2[(size_t)nC * 32 + q];
        uint2 uD = K2[(size_t)nD * 32 + q];
        a0 += (bflo(uA.x) + bflo(uB.x)) + (bflo(uC.x) + bflo(uD.x));
        a1 += (bfhi(uA.x) + bfhi(uB.x)) + (bfhi(uC.x) + bfhi(uD.x));
        a2 += (bflo(uA.y) + bflo(uB.y)) + (bflo(uC.y) + bflo(uD.y));
        a3 += (bfhi(uA.y) + bfhi(uB.y)) + (bfhi(uC.y) + bfhi(uD.y));
    }
    for (; p < end; p += 2) {
        int pi = p + half;
        bool valid = pi < end;
        int nn = members[valid ? pi : beg];
        uint2 u = K2[(size_t)nn * 32 + q];
        float w = valid ? 1.f : 0.f;
        a0 += w * bflo(u.x);
        a1 += w * bfhi(u.x);
        a2 += w * bflo(u.y);
        a3 += w * bfhi(u.y);
    }
    a0 += __shfl_xor(a0, 32);
    a1 += __shfl_xor(a1, 32);
    a2 += __shfl_xor(a2, 32);
    a3 += __shfl_xor(a3, 32);
    if (half == 0)
        he_feat2[(size_t)h * 32 + q] = make_uint2(packbf(a0, a1), packbf(a2, a3));
}

// ---------------------------------------------------------------------------
// Stages 3-5 fused: per-node online softmax + weighted accumulate (half-wave).
// ---------------------------------------------------------------------------
__global__ void fused_attn(const float* __restrict__ Q,
                           const uint2* __restrict__ he_feat2,
                           const int* __restrict__ node_ptr,
                           const int* __restrict__ hes,
                           float* __restrict__ node_out, int N)
{
    const float SC = 0.17677669529663687f;   // 1/sqrt(32)
    const float NEG = -1e30f;
    int n = blockIdx.x * 4 + (threadIdx.x >> 6);
    if (n >= N) return;
    int lane = threadIdx.x & 63;
    int half = lane >> 5;
    int q    = lane & 31;
    int beg = node_ptr[n], end = node_ptr[n + 1];
    float4 q4 = ((const float4*)Q)[(size_t)n * 32 + q];
    float m = NEG, s = 0.f;
    float a0 = 0.f, a1 = 0.f, a2 = 0.f, a3 = 0.f;

    int p = beg;
    for (; p + 7 < end; p += 8) {
        int hA = hes[p     + half];
        int hB = hes[p + 2 + half];
        int hC = hes[p + 4 + half];
        int hD = hes[p + 6 + half];
        uint2 uA = he_feat2[(size_t)hA * 32 + q];
        uint2 uB = he_feat2[(size_t)hB * 32 + q];
        uint2 uC = he_feat2[(size_t)hC * 32 + q];
        uint2 uD = he_feat2[(size_t)hD * 32 + q];
        float fA0 = bflo(uA.x), fA1 = bfhi(uA.x), fA2 = bflo(uA.y), fA3 = bfhi(uA.y);
        float fB0 = bflo(uB.x), fB1 = bfhi(uB.x), fB2 = bflo(uB.y), fB3 = bfhi(uB.y);
        float fC0 = bflo(uC.x), fC1 = bfhi(uC.x), fC2 = bflo(uC.y), fC3 = bfhi(uC.y);
        float fD0 = bflo(uD.x), fD1 = bfhi(uD.x), fD2 = bflo(uD.y), fD3 = bfhi(uD.y);
        float dA = q4.x * fA0 + q4.y * fA1 + q4.z * fA2 + q4.w * fA3;
        float dB = q4.x * fB0 + q4.y * fB1 + q4.z * fB2 + q4.w * fB3;
        float dC = q4.x * fC0 + q4.y * fC1 + q4.z * fC2 + q4.w * fC3;
        float dD = q4.x * fD0 + q4.y * fD1 + q4.z * fD2 + q4.w * fD3;
        #pragma unroll
        for (int off = 1; off <= 4; off <<= 1) {
            dA += __shfl_xor(dA, off);
            dB += __shfl_xor(dB, off);
            dC += __shfl_xor(dC, off);
            dD += __shfl_xor(dD, off);
        }
        float aA = dA * SC, aB = dB * SC, aC = dC * SC, aD = dD * SC;
        float newm = fmaxf(m, fmaxf(fmaxf(aA, aB), fmaxf(aC, aD)));
        float scale = __expf(m - newm);
        float wA = __expf(aA - newm), wB = __expf(aB - newm);
        float wC = __expf(aC - newm), wD = __expf(aD - newm);
        s  = s  * scale + ((wA + wB) + (wC + wD));
        a0 = a0 * scale + ((wA * fA0 + wB * fB0) + (wC * fC0 + wD * fD0));
        a1 = a1 * scale + ((wA * fA1 + wB * fB1) + (wC * fC1 + wD * fD1));
        a2 = a2 * scale + ((wA * fA2 + wB * fB2) + (wC * fC2 + wD * fD2));
        a3 = a3 * scale + ((wA * fA3 + wB * fB3) + (wC * fC3 + wD * fD3));
        m = newm;
    }
    for (; p < end; p += 2) {
        int pi = p + half;
        bool valid = pi < end;
        int h = hes[valid ? pi : beg];
        uint2 u = he_feat2[(size_t)h * 32 + q];
        float f0 = bflo(u.x), f1 = bfhi(u.x), f2 = bflo(u.y), f3 = bfhi(u.y);
        float d = q4.x * f0 + q4.y * f1 + q4.z * f2 + q4.w * f3;
        d += __shfl_xor(d, 1);
        d += __shfl_xor(d, 2);
        d += __shfl_xor(d, 4);
        float a = d * SC;
        float newm = valid ? fmaxf(m, a) : m;
        float scale = __expf(m - newm);
        float w = valid ? __expf(a - newm) : 0.f;
        s  = s  * scale + w;
        a0 = a0 * scale + w * f0;
        a1 = a1 * scale + w * f1;
        a2 = a2 * scale + w * f2;
        a3 = a3 * scale + w * f3;
        m = newm;
    }
    float mo = __shfl_xor(m, 32);
    float so = __shfl_xor(s, 32);
    float b0 = __shfl_xor(a0, 32);
    float b1 = __shfl_xor(a1, 32);
    float b2 = __shfl_xor(a2, 32);
    float b3 = __shfl_xor(a3, 32);
    float M  = fmaxf(m, mo);
    float e1 = __expf(m - M), e2 = __expf(mo - M);
    float S  = s * e1 + so * e2;
    float inv = 1.f / (S + 1e-16f);
    if (half == 0) {
        float4 o;
        o.x = (a0 * e1 + b0 * e2) * inv;
        o.y = (a1 * e1 + b1 * e2) * inv;
        o.z = (a2 * e1 + b2 * e2) * inv;
        o.w = (a3 * e1 + b3 * e2) * inv;
        ((float4*)node_out)[(size_t)n * 32 + q] = o;
    }
}

// ---------------------------------------------------------------------------
extern "C" void kernel_launch(void* const* d_in, const int* in_sizes, int n_in,
                              void* d_out, int out_size, void* d_ws, size_t ws_size,
                              hipStream_t stream)
{
    const float* x        = (const float*)d_in[0];
    const int*   node_idx = (const int*)d_in[1];
    const int*   he_idx   = (const int*)d_in[2];
    const float* Wk       = (const float*)d_in[3];
    const float* bk       = (const float*)d_in[4];
    const float* Wq       = (const float*)d_in[5];
    const float* bq       = (const float*)d_in[6];
    const float* Wa       = (const float*)d_in[7];
    const float* ba       = (const float*)d_in[8];
    float*       out      = (float*)d_out;

    const int N = in_sizes[0] / D;
    const int E = in_sizes[1];

    const int nblk  = (E + BIN_CH - 1) / BIN_CH;
    const int nb_he = (NUM_HE + 31) >> 5;    // 625 buckets of 32 hyperedges
    const int nb_nd = (N + 127) >> 7;        // 782 buckets of 128 nodes
    const int nb_mx = (nb_he > nb_nd) ? nb_he : nb_nd;

    // Workspace layout.
    float* ws      = (float*)d_ws;
    float* Kbuf    = ws;                               // N*D region (bf16 K / later f32 node_out)
    float* Qbuf    = Kbuf    + (size_t)N * D;          // N*D f32 (Q)
    float* he_feat = Qbuf    + (size_t)N * D;          // NUM_HE*D region (bf16 in half)
    unsigned short* wfrag = (unsigned short*)(he_feat + (size_t)NUM_HE * D); // 3*32768
    int*   ibase   = (int*)(wfrag + 3 * 32768);
    int*   he_ptr  = ibase;                            // NUM_HE+1
    int*   nd_ptr  = he_ptr  + (NUM_HE + 1);           // N+1
    int*   he_mem  = nd_ptr  + (N + 1);                // E (node ids by he)
    int*   nd_he   = he_mem  + E;                      // E (he ids by node)
    int*   counts  = nd_he   + E;                      // nblk*nb_mx (shared he/nd)
    int*   boffs   = counts  + (size_t)nblk * nb_mx;   // nblk*nb_mx
    int*   btot    = boffs   + (size_t)nblk * nb_mx;   // nb_mx
    int*   bbase   = btot    + nb_mx;                  // nb_mx
    uintptr_t sp   = ((uintptr_t)(bbase + nb_mx) + 7) & ~(uintptr_t)7;
    uint2* staging = (uint2*)sp;                       // E pairs (shared he/nd)

    const int gemm_grid = (N + 127) / 128;

    // W fragments (hi/lo) for all three projections
    wprep<<<(3 * 16384 + 255) / 256, 256, 0, stream>>>(Wk, Wq, Wa, wfrag);

    // Stage 1: K (bf16 out), Q (fp32 out) projections
    gemm_split<false, true><<<gemm_grid, 256, 0, stream>>>(
        x, nullptr, wfrag, wfrag + 16384, bk, Kbuf, N);
    gemm_split<false, false><<<gemm_grid, 256, 0, stream>>>(
        x, nullptr, wfrag + 32768, wfrag + 49152, bq, Qbuf, N);

    // CSR by hyperedge (SHIFT=5), zero global atomics
    stage_pairs<5, 640><<<nblk, 256, 0, stream>>>(
        he_idx, node_idx, counts, boffs, staging, E, nb_he);
    bucket_tot<<<(nb_he + 3) / 4, 256, 0, stream>>>(counts, btot, nb_he, nblk);
    bucket_scan<<<1, 1024, 0, stream>>>(btot, bbase, he_ptr, NUM_HE, nb_he, E);
    fill_csr<5><<<nb_he, 256, 0, stream>>>(
        staging, counts, boffs, bbase, he_ptr, he_mem, NUM_HE, nb_he, nblk);

    // Stage 2: hyperedge aggregation (uses he CSR; staging then free for nd)
    gather_he<<<(NUM_HE + 3) / 4, 256, 0, stream>>>(
        (const uint2*)Kbuf, he_ptr, he_mem, (uint2*)he_feat, NUM_HE);

    // CSR by node (SHIFT=7), reusing counts/boffs/btot/bbase/staging
    stage_pairs<7, 800><<<nblk, 256, 0, stream>>>(
        node_idx, he_idx, counts, boffs, staging, E, nb_nd);
    bucket_tot<<<(nb_nd + 3) / 4, 256, 0, stream>>>(counts, btot, nb_nd, nblk);
    bucket_scan<<<1, 1024, 0, stream>>>(btot, bbase, nd_ptr, N, nb_nd, E);
    fill_csr<7><<<nb_nd, 256, 0, stream>>>(
        staging, counts, boffs, bbase, nd_ptr, nd_he, N, nb_nd, nblk);

    // Stages 3-5: fused attention (bf16 K dead; Kbuf region becomes f32 node_out)
    fused_attn<<<(N + 3) / 4, 256, 0, stream>>>(
        Qbuf, (const uint2*)he_feat, nd_ptr, nd_he, Kbuf, N);

    // Stage 6: residual folded into A-load; fp32 out
    gemm_split<true, false><<<gemm_grid, 256, 0, stream>>>(
        Kbuf, x, wfrag + 65536, wfrag + 81920, ba, out, N);
}

// Round 10
// 276.547 us; speedup vs baseline: 4.8655x; 1.1748x over previous
//
#include <hip/hip_runtime.h>
#include <math.h>

#define D 128
#define HEADS 4
#define DK 32
#define NUM_HE 20000
#define BIN_CH 4096

typedef short bf16x8 __attribute__((ext_vector_type(8)));
typedef float f32x4  __attribute__((ext_vector_type(4)));

__device__ __forceinline__ unsigned short f2bf(float f) {
    unsigned int u = __float_as_uint(f);
    u = (u + 0x7fffu + ((u >> 16) & 1u)) >> 16;
    return (unsigned short)u;
}
__device__ __forceinline__ float bf2f(unsigned short h) {
    return __uint_as_float(((unsigned int)h) << 16);
}
__device__ __forceinline__ float bflo(unsigned int u) {
    return __uint_as_float(u << 16);
}
__device__ __forceinline__ float bfhi(unsigned int u) {
    return __uint_as_float(u & 0xffff0000u);
}
__device__ __forceinline__ unsigned int packbf(float lo, float hi) {
    return (unsigned int)f2bf(lo) | ((unsigned int)f2bf(hi) << 16);
}
// butterfly add over 8-lane groups via DPP (VALU pipe, no LDS)
template<int CTRL>
__device__ __forceinline__ float dppadd(float v) {
    int s = __builtin_amdgcn_update_dpp(0, __float_as_int(v), CTRL, 0xf, 0xf, true);
    return v + __int_as_float(s);
}
__device__ __forceinline__ float red8(float v) {
    v = dppadd<0xB1>(v);    // quad_perm [1,0,3,2]  (xor 1)
    v = dppadd<0x4E>(v);    // quad_perm [2,3,0,1]  (xor 2)
    v = dppadd<0x141>(v);   // row_half_mirror      (xor 4 equivalent)
    return v;
}

// ---------------------------------------------------------------------------
// W preprocessing: fragment-order Wk|Wq|Wa as bf16 hi/lo.
// ---------------------------------------------------------------------------
__global__ void wprep(const float* __restrict__ Wk, const float* __restrict__ Wq,
                      const float* __restrict__ Wa, unsigned short* __restrict__ dst)
{
    int t = blockIdx.x * blockDim.x + threadIdx.x;
    if (t >= 3 * 16384) return;
    int w = t >> 14, rem = t & 16383;
    int ks = rem >> 12, nf = (rem >> 9) & 7, lane = (rem >> 3) & 63, j = rem & 7;
    int r = ks * 32 + (lane >> 4) * 8 + j;
    int c = nf * 16 + (lane & 15);
    const float* W = (w == 0) ? Wk : (w == 1) ? Wq : Wa;
    float v = W[r * 128 + c];
    unsigned short h = f2bf(v);
    dst[(size_t)w * 32768 + rem]         = h;
    dst[(size_t)w * 32768 + 16384 + rem] = f2bf(v - bf2f(h));
}

// ---------------------------------------------------------------------------
// Fused K+Q projection: A-fragments built once, two weight matrices.
// K out bf16, Q out fp32.
// ---------------------------------------------------------------------------
__global__ __launch_bounds__(256) void gemm_kq(
    const float* __restrict__ A,
    const unsigned short* __restrict__ BhK, const unsigned short* __restrict__ BlK,
    const unsigned short* __restrict__ BhQ, const unsigned short* __restrict__ BlQ,
    const float* __restrict__ bk, const float* __restrict__ bq,
    unsigned short* __restrict__ K, float* __restrict__ Q, int M)
{
    const int lane = threadIdx.x & 63;
    const int wv   = threadIdx.x >> 6;
    const int r0   = blockIdx.x * 128 + wv * 32;
    const int lr   = lane & 15;
    const int kg   = lane >> 4;

    f32x4 ack[2][8], acq[2][8];
    #pragma unroll
    for (int m = 0; m < 2; ++m)
        #pragma unroll
        for (int n = 0; n < 8; ++n) {
            ack[m][n] = (f32x4){0.f, 0.f, 0.f, 0.f};
            acq[m][n] = (f32x4){0.f, 0.f, 0.f, 0.f};
        }

    int row[2];
    row[0] = min(r0 + lr,      M - 1);
    row[1] = min(r0 + 16 + lr, M - 1);

    for (int ks = 0; ks < 4; ++ks) {
        bf16x8 ah[2], al[2];
        #pragma unroll
        for (int m = 0; m < 2; ++m) {
            const float* p = A + (size_t)row[m] * D + ks * 32 + kg * 8;
            float4 v0 = *(const float4*)p;
            float4 v1 = *(const float4*)(p + 4);
            float vv[8] = {v0.x, v0.y, v0.z, v0.w, v1.x, v1.y, v1.z, v1.w};
            #pragma unroll
            for (int j = 0; j < 8; ++j) {
                unsigned short h = f2bf(vv[j]);
                ah[m][j] = (short)h;
                al[m][j] = (short)f2bf(vv[j] - bf2f(h));
            }
        }
        #pragma unroll
        for (int nf = 0; nf < 8; ++nf) {
            const int boff = ((ks * 8 + nf) * 64 + lane) * 8;
            bf16x8 bhk = *(const bf16x8*)(const void*)(BhK + boff);
            bf16x8 blk = *(const bf16x8*)(const void*)(BlK + boff);
            bf16x8 bhq = *(const bf16x8*)(const void*)(BhQ + boff);
            bf16x8 blq = *(const bf16x8*)(const void*)(BlQ + boff);
            #pragma unroll
            for (int m = 0; m < 2; ++m) {
                ack[m][nf] = __builtin_amdgcn_mfma_f32_16x16x32_bf16(ah[m], bhk, ack[m][nf], 0, 0, 0);
                ack[m][nf] = __builtin_amdgcn_mfma_f32_16x16x32_bf16(ah[m], blk, ack[m][nf], 0, 0, 0);
                ack[m][nf] = __builtin_amdgcn_mfma_f32_16x16x32_bf16(al[m], bhk, ack[m][nf], 0, 0, 0);
                acq[m][nf] = __builtin_amdgcn_mfma_f32_16x16x32_bf16(ah[m], bhq, acq[m][nf], 0, 0, 0);
                acq[m][nf] = __builtin_amdgcn_mfma_f32_16x16x32_bf16(ah[m], blq, acq[m][nf], 0, 0, 0);
                acq[m][nf] = __builtin_amdgcn_mfma_f32_16x16x32_bf16(al[m], bhq, acq[m][nf], 0, 0, 0);
            }
        }
    }

    #pragma unroll
    for (int nf = 0; nf < 8; ++nf) {
        int col = nf * 16 + lr;
        float bkv = bk[col], bqv = bq[col];
        #pragma unroll
        for (int m = 0; m < 2; ++m) {
            #pragma unroll
            for (int j = 0; j < 4; ++j) {
                int gr = r0 + m * 16 + kg * 4 + j;
                if (gr < M) {
                    K[(size_t)gr * D + col] = f2bf(ack[m][nf][j] + bkv);
                    Q[(size_t)gr * D + col] = acq[m][nf][j] + bqv;
                }
            }
        }
    }
}

// ---------------------------------------------------------------------------
// Output projection: A = bf16 node_out + fp32 residual x; fp32 out.
// ---------------------------------------------------------------------------
__global__ __launch_bounds__(256) void gemm_out(
    const unsigned short* __restrict__ A, const float* __restrict__ R,
    const unsigned short* __restrict__ Bh, const unsigned short* __restrict__ Bl,
    const float* __restrict__ bias, float* __restrict__ C, int M)
{
    const int lane = threadIdx.x & 63;
    const int wv   = threadIdx.x >> 6;
    const int r0   = blockIdx.x * 128 + wv * 32;
    const int lr   = lane & 15;
    const int kg   = lane >> 4;

    f32x4 acc[2][8];
    #pragma unroll
    for (int m = 0; m < 2; ++m)
        #pragma unroll
        for (int n = 0; n < 8; ++n) acc[m][n] = (f32x4){0.f, 0.f, 0.f, 0.f};

    int row[2];
    row[0] = min(r0 + lr,      M - 1);
    row[1] = min(r0 + 16 + lr, M - 1);

    for (int ks = 0; ks < 4; ++ks) {
        bf16x8 ah[2], al[2];
        #pragma unroll
        for (int m = 0; m < 2; ++m) {
            const unsigned short* pa = A + (size_t)row[m] * D + ks * 32 + kg * 8;
            uint4 av = *(const uint4*)(const void*)pa;
            const float* q = R + (size_t)row[m] * D + ks * 32 + kg * 8;
            float4 u0 = *(const float4*)q;
            float4 u1 = *(const float4*)(q + 4);
            float vv[8];
            vv[0] = bflo(av.x) + u0.x; vv[1] = bfhi(av.x) + u0.y;
            vv[2] = bflo(av.y) + u0.z; vv[3] = bfhi(av.y) + u0.w;
            vv[4] = bflo(av.z) + u1.x; vv[5] = bfhi(av.z) + u1.y;
            vv[6] = bflo(av.w) + u1.z; vv[7] = bfhi(av.w) + u1.w;
            #pragma unroll
            for (int j = 0; j < 8; ++j) {
                unsigned short h = f2bf(vv[j]);
                ah[m][j] = (short)h;
                al[m][j] = (short)f2bf(vv[j] - bf2f(h));
            }
        }
        #pragma unroll
        for (int nf = 0; nf < 8; ++nf) {
            const int boff = ((ks * 8 + nf) * 64 + lane) * 8;
            bf16x8 bh = *(const bf16x8*)(const void*)(Bh + boff);
            bf16x8 bl = *(const bf16x8*)(const void*)(Bl + boff);
            #pragma unroll
            for (int m = 0; m < 2; ++m) {
                acc[m][nf] = __builtin_amdgcn_mfma_f32_16x16x32_bf16(ah[m], bh, acc[m][nf], 0, 0, 0);
                acc[m][nf] = __builtin_amdgcn_mfma_f32_16x16x32_bf16(ah[m], bl, acc[m][nf], 0, 0, 0);
                acc[m][nf] = __builtin_amdgcn_mfma_f32_16x16x32_bf16(al[m], bh, acc[m][nf], 0, 0, 0);
            }
        }
    }

    #pragma unroll
    for (int nf = 0; nf < 8; ++nf) {
        int col = nf * 16 + lr;
        float bv = bias[col];
        #pragma unroll
        for (int m = 0; m < 2; ++m) {
            #pragma unroll
            for (int j = 0; j < 4; ++j) {
                int gr = r0 + m * 16 + kg * 4 + j;
                if (gr < M) C[(size_t)gr * D + col] = acc[m][nf][j] + bv;
            }
        }
    }
}

// ---------------------------------------------------------------------------
// CSR construction with ZERO global atomics (unchanged from R8).
// ---------------------------------------------------------------------------
template<int SHIFT, int MAXNB>
__global__ __launch_bounds__(256) void stage_pairs(
    const int* __restrict__ seg, const int* __restrict__ val,
    int* __restrict__ counts, int* __restrict__ boffs,
    uint2* __restrict__ staging, int E, int nb)
{
    __shared__ int hist[MAXNB];
    __shared__ int offs[MAXNB];
    __shared__ int wtot[4];
    const int tid  = threadIdx.x;
    const int lane = tid & 63;
    const int wid  = tid >> 6;
    const int e0   = blockIdx.x * BIN_CH;

    for (int i = tid; i < nb; i += 256) hist[i] = 0;
    __syncthreads();

    int myseg[16], myval[16], myrank[16];
    #pragma unroll
    for (int j = 0; j < 16; ++j) {
        int e = e0 + j * 256 + tid;
        if (e < E) {
            int s = seg[e];
            myseg[j]  = s;
            myval[j]  = val[e];
            myrank[j] = atomicAdd(&hist[s >> SHIFT], 1);
        } else myseg[j] = -1;
    }
    __syncthreads();

    const int i0 = tid * 4;
    int v0 = (i0 + 0 < nb) ? hist[i0 + 0] : 0;
    int v1 = (i0 + 1 < nb) ? hist[i0 + 1] : 0;
    int v2 = (i0 + 2 < nb) ? hist[i0 + 2] : 0;
    int v3 = (i0 + 3 < nb) ? hist[i0 + 3] : 0;
    int tsum = v0 + v1 + v2 + v3;
    int x = tsum;
    #pragma unroll
    for (int off = 1; off < 64; off <<= 1) {
        int y = __shfl_up(x, off);
        if (lane >= off) x += y;
    }
    if (lane == 63) wtot[wid] = x;
    __syncthreads();
    if (tid == 0) {
        int r = 0;
        #pragma unroll
        for (int w = 0; w < 4; ++w) { int c = wtot[w]; wtot[w] = r; r += c; }
    }
    __syncthreads();
    int base = wtot[wid] + x - tsum;
    if (i0 + 0 < nb) offs[i0 + 0] = base; base += v0;
    if (i0 + 1 < nb) offs[i0 + 1] = base; base += v1;
    if (i0 + 2 < nb) offs[i0 + 2] = base; base += v2;
    if (i0 + 3 < nb) offs[i0 + 3] = base;
    __syncthreads();

    for (int i = tid; i < nb; i += 256) {
        counts[(size_t)blockIdx.x * nb + i] = hist[i];
        boffs [(size_t)blockIdx.x * nb + i] = offs[i];
    }
    #pragma unroll
    for (int j = 0; j < 16; ++j) {
        if (myseg[j] >= 0) {
            int b = myseg[j] >> SHIFT;
            staging[e0 + offs[b] + myrank[j]] =
                make_uint2((unsigned)myseg[j], (unsigned)myval[j]);
        }
    }
}

__global__ void bucket_tot(const int* __restrict__ counts, int* __restrict__ btot,
                           int nb, int nblk)
{
    int k = blockIdx.x * 4 + (threadIdx.x >> 6);
    if (k >= nb) return;
    int lane = threadIdx.x & 63;
    int s = 0;
    for (int b = lane; b < nblk; b += 64) s += counts[(size_t)b * nb + k];
    #pragma unroll
    for (int off = 1; off < 64; off <<= 1) s += __shfl_xor(s, off);
    if (lane == 0) btot[k] = s;
}

__global__ void bucket_scan(const int* __restrict__ btot, int* __restrict__ bbase,
                            int* __restrict__ ptr, int nseg, int nb, int Etot)
{
    __shared__ int wsum[16];
    const int tid = threadIdx.x, lane = tid & 63, wid = tid >> 6;
    int v = (tid < nb) ? btot[tid] : 0;
    int x = v;
    #pragma unroll
    for (int off = 1; off < 64; off <<= 1) {
        int y = __shfl_up(x, off);
        if (lane >= off) x += y;
    }
    if (lane == 63) wsum[wid] = x;
    __syncthreads();
    if (wid == 0) {
        int wv = (lane < 16) ? wsum[lane] : 0;
        #pragma unroll
        for (int off = 1; off < 16; off <<= 1) {
            int y = __shfl_up(wv, off);
            if (lane >= off) wv += y;
        }
        if (lane < 16) wsum[lane] = wv;
    }
    __syncthreads();
    int base = (wid > 0) ? wsum[wid - 1] : 0;
    if (tid < nb) bbase[tid] = base + x - v;
    if (tid == 0) ptr[nseg] = Etot;
}

template<int SHIFT>
__global__ __launch_bounds__(256) void fill_csr(
    const uint2* __restrict__ staging, const int* __restrict__ counts,
    const int* __restrict__ boffs, const int* __restrict__ bbase,
    int* __restrict__ ptr, int* __restrict__ outv,
    int nseg, int nb, int nblk)
{
    __shared__ int cur[1 << SHIFT];
    const int tid = threadIdx.x;
    const int k   = blockIdx.x;
    const int s0  = k << SHIFT;
    const int NS  = min(1 << SHIFT, nseg - s0);
    for (int i = tid; i < NS; i += 256) cur[i] = 0;
    __syncthreads();
    for (int b = tid; b < nblk; b += 256) {
        int c   = counts[(size_t)b * nb + k];
        int off = b * BIN_CH + boffs[(size_t)b * nb + k];
        for (int i = 0; i < c; ++i) {
            int s = (int)staging[off + i].x;
            atomicAdd(&cur[s - s0], 1);
        }
    }
    __syncthreads();
    if (tid == 0) {
        int run = bbase[k];
        for (int i = 0; i < NS; ++i) {
            int c = cur[i];
            cur[i] = run;
            ptr[s0 + i] = run;
            run += c;
        }
    }
    __syncthreads();
    for (int b = tid; b < nblk; b += 256) {
        int c   = counts[(size_t)b * nb + k];
        int off = b * BIN_CH + boffs[(size_t)b * nb + k];
        for (int i = 0; i < c; ++i) {
            uint2 pv = staging[off + i];
            int pos = atomicAdd(&cur[(int)pv.x - s0], 1);
            outv[pos] = (int)pv.y;
        }
    }
}

// ---------------------------------------------------------------------------
// Stage 2: he_feat[h] = sum of member K rows (half-wave layout).
// ---------------------------------------------------------------------------
__global__ void gather_he(const uint2* __restrict__ K2,
                          const int* __restrict__ he_ptr,
                          const int* __restrict__ members,
                          uint2* __restrict__ he_feat2, int HE)
{
    int h = blockIdx.x * 4 + (threadIdx.x >> 6);
    if (h >= HE) return;
    int lane = threadIdx.x & 63;
    int half = lane >> 5;
    int q    = lane & 31;
    int beg = he_ptr[h], end = he_ptr[h + 1];
    float a0 = 0.f, a1 = 0.f, a2 = 0.f, a3 = 0.f;
    int p = beg;
    for (; p + 7 < end; p += 8) {
        int nA = members[p     + half];
        int nB = members[p + 2 + half];
        int nC = members[p + 4 + half];
        int nD = members[p + 6 + half];
        uint2 uA = K2[(size_t)nA * 32 + q];
        uint2 uB = K2[(size_t)nB * 32 + q];
        uint2 uC = K2[(size_t)nC * 32 + q];
        uint2 uD = K2[(size_t)nD * 32 + q];
        a0 += (bflo(uA.x) + bflo(uB.x)) + (bflo(uC.x) + bflo(uD.x));
        a1 += (bfhi(uA.x) + bfhi(uB.x)) + (bfhi(uC.x) + bfhi(uD.x));
        a2 += (bflo(uA.y) + bflo(uB.y)) + (bflo(uC.y) + bflo(uD.y));
        a3 += (bfhi(uA.y) + bfhi(uB.y)) + (bfhi(uC.y) + bfhi(uD.y));
    }
    for (; p < end; p += 2) {
        int pi = p + half;
        bool valid = pi < end;
        int nn = members[valid ? pi : beg];
        uint2 u = K2[(size_t)nn * 32 + q];
        float w = valid ? 1.f : 0.f;
        a0 += w * bflo(u.x);
        a1 += w * bfhi(u.x);
        a2 += w * bflo(u.y);
        a3 += w * bfhi(u.y);
    }
    a0 += __shfl_xor(a0, 32);
    a1 += __shfl_xor(a1, 32);
    a2 += __shfl_xor(a2, 32);
    a3 += __shfl_xor(a3, 32);
    if (half == 0)
        he_feat2[(size_t)h * 32 + q] = make_uint2(packbf(a0, a1), packbf(a2, a3));
}

// ---------------------------------------------------------------------------
// Stages 3-5 fused: per-node online softmax + weighted accumulate.
// Half-wave layout; DPP 8-lane reduce; single masked 8-wide loop (no serial
// tail); 1/sqrt(DK) folded into Q; bf16 node_out.
// ---------------------------------------------------------------------------
__global__ void fused_attn(const float* __restrict__ Q,
                           const uint2* __restrict__ he_feat2,
                           const int* __restrict__ node_ptr,
                           const int* __restrict__ hes,
                           uint2* __restrict__ node_out_bf, int N)
{
    const float SC = 0.17677669529663687f;   // 1/sqrt(32)
    const float NEG = -1e30f;
    int n = blockIdx.x * 4 + (threadIdx.x >> 6);
    if (n >= N) return;
    int lane = threadIdx.x & 63;
    int half = lane >> 5;
    int q    = lane & 31;
    int beg = node_ptr[n], end = node_ptr[n + 1];
    float4 q4 = ((const float4*)Q)[(size_t)n * 32 + q];
    q4.x *= SC; q4.y *= SC; q4.z *= SC; q4.w *= SC;
    float m = NEG, s = 0.f;
    float a0 = 0.f, a1 = 0.f, a2 = 0.f, a3 = 0.f;

    for (int p = beg; p < end; p += 8) {
        const int last = end - 1;
        int iA = p     + half, iB = p + 2 + half;
        int iC = p + 4 + half, iD = p + 6 + half;
        bool vA = iA <= last, vB = iB <= last, vC = iC <= last, vD = iD <= last;
        int hA = hes[vA ? iA : last];
        int hB = hes[vB ? iB : last];
        int hC = hes[vC ? iC : last];
        int hD = hes[vD ? iD : last];
        uint2 uA = he_feat2[(size_t)hA * 32 + q];
        uint2 uB = he_feat2[(size_t)hB * 32 + q];
        uint2 uC = he_feat2[(size_t)hC * 32 + q];
        uint2 uD = he_feat2[(size_t)hD * 32 + q];
        float fA0 = bflo(uA.x), fA1 = bfhi(uA.x), fA2 = bflo(uA.y), fA3 = bfhi(uA.y);
        float fB0 = bflo(uB.x), fB1 = bfhi(uB.x), fB2 = bflo(uB.y), fB3 = bfhi(uB.y);
        float fC0 = bflo(uC.x), fC1 = bfhi(uC.x), fC2 = bflo(uC.y), fC3 = bfhi(uC.y);
        float fD0 = bflo(uD.x), fD1 = bfhi(uD.x), fD2 = bflo(uD.y), fD3 = bfhi(uD.y);
        float dA = q4.x * fA0 + q4.y * fA1 + q4.z * fA2 + q4.w * fA3;
        float dB = q4.x * fB0 + q4.y * fB1 + q4.z * fB2 + q4.w * fB3;
        float dC = q4.x * fC0 + q4.y * fC1 + q4.z * fC2 + q4.w * fC3;
        float dD = q4.x * fD0 + q4.y * fD1 + q4.z * fD2 + q4.w * fD3;
        dA = red8(dA); dB = red8(dB); dC = red8(dC); dD = red8(dD);
        float aA = vA ? dA : NEG;
        float aB = vB ? dB : NEG;
        float aC = vC ? dC : NEG;
        float aD = vD ? dD : NEG;
        float newm = fmaxf(m, fmaxf(fmaxf(aA, aB), fmaxf(aC, aD)));
        float scale = __expf(m - newm);
        float wA = __expf(aA - newm), wB = __expf(aB - newm);
        float wC = __expf(aC - newm), wD = __expf(aD - newm);
        s  = s  * scale + ((wA + wB) + (wC + wD));
        a0 = a0 * scale + ((wA * fA0 + wB * fB0) + (wC * fC0 + wD * fD0));
        a1 = a1 * scale + ((wA * fA1 + wB * fB1) + (wC * fC1 + wD * fD1));
        a2 = a2 * scale + ((wA * fA2 + wB * fB2) + (wC * fC2 + wD * fD2));
        a3 = a3 * scale + ((wA * fA3 + wB * fB3) + (wC * fC3 + wD * fD3));
        m = newm;
    }

    // merge the two halves
    float mo = __shfl_xor(m, 32);
    float so = __shfl_xor(s, 32);
    float b0 = __shfl_xor(a0, 32);
    float b1 = __shfl_xor(a1, 32);
    float b2 = __shfl_xor(a2, 32);
    float b3 = __shfl_xor(a3, 32);
    float M  = fmaxf(m, mo);
    float e1 = __expf(m - M), e2 = __expf(mo - M);
    float S  = s * e1 + so * e2;
    float inv = 1.f / (S + 1e-16f);
    if (half == 0) {
        float o0 = (a0 * e1 + b0 * e2) * inv;
        float o1 = (a1 * e1 + b1 * e2) * inv;
        float o2 = (a2 * e1 + b2 * e2) * inv;
        float o3 = (a3 * e1 + b3 * e2) * inv;
        node_out_bf[(size_t)n * 32 + q] = make_uint2(packbf(o0, o1), packbf(o2, o3));
    }
}

// ---------------------------------------------------------------------------
extern "C" void kernel_launch(void* const* d_in, const int* in_sizes, int n_in,
                              void* d_out, int out_size, void* d_ws, size_t ws_size,
                              hipStream_t stream)
{
    const float* x        = (const float*)d_in[0];
    const int*   node_idx = (const int*)d_in[1];
    const int*   he_idx   = (const int*)d_in[2];
    const float* Wk       = (const float*)d_in[3];
    const float* bk       = (const float*)d_in[4];
    const float* Wq       = (const float*)d_in[5];
    const float* bq       = (const float*)d_in[6];
    const float* Wa       = (const float*)d_in[7];
    const float* ba       = (const float*)d_in[8];
    float*       out      = (float*)d_out;

    const int N = in_sizes[0] / D;
    const int E = in_sizes[1];

    const int nblk  = (E + BIN_CH - 1) / BIN_CH;
    const int nb_he = (NUM_HE + 31) >> 5;    // 625 buckets of 32 hyperedges
    const int nb_nd = (N + 127) >> 7;        // 782 buckets of 128 nodes
    const int nb_mx = (nb_he > nb_nd) ? nb_he : nb_nd;

    // Workspace layout.
    float* ws      = (float*)d_ws;
    float* Kbuf    = ws;                               // N*D region: bf16 K, later bf16 node_out
    float* Qbuf    = Kbuf    + (size_t)N * D;          // N*D f32 (Q)
    float* he_feat = Qbuf    + (size_t)N * D;          // NUM_HE*D region (bf16 in half)
    unsigned short* wfrag = (unsigned short*)(he_feat + (size_t)NUM_HE * D); // 3*32768
    int*   ibase   = (int*)(wfrag + 3 * 32768);
    int*   he_ptr  = ibase;                            // NUM_HE+1
    int*   nd_ptr  = he_ptr  + (NUM_HE + 1);           // N+1
    int*   he_mem  = nd_ptr  + (N + 1);                // E (node ids by he)
    int*   nd_he   = he_mem  + E;                      // E (he ids by node)
    int*   counts  = nd_he   + E;                      // nblk*nb_mx (shared he/nd)
    int*   boffs   = counts  + (size_t)nblk * nb_mx;   // nblk*nb_mx
    int*   btot    = boffs   + (size_t)nblk * nb_mx;   // nb_mx
    int*   bbase   = btot    + nb_mx;                  // nb_mx
    uintptr_t sp   = ((uintptr_t)(bbase + nb_mx) + 7) & ~(uintptr_t)7;
    uint2* staging = (uint2*)sp;                       // E pairs (shared he/nd)

    const int gemm_grid = (N + 127) / 128;

    // W fragments (hi/lo) for all three projections
    wprep<<<(3 * 16384 + 255) / 256, 256, 0, stream>>>(Wk, Wq, Wa, wfrag);

    // Stage 1: fused K (bf16) + Q (fp32) projection — x read once
    gemm_kq<<<gemm_grid, 256, 0, stream>>>(
        x, wfrag, wfrag + 16384, wfrag + 32768, wfrag + 49152,
        bk, bq, (unsigned short*)Kbuf, Qbuf, N);

    // CSR by hyperedge (SHIFT=5), zero global atomics
    stage_pairs<5, 640><<<nblk, 256, 0, stream>>>(
        he_idx, node_idx, counts, boffs, staging, E, nb_he);
    bucket_tot<<<(nb_he + 3) / 4, 256, 0, stream>>>(counts, btot, nb_he, nblk);
    bucket_scan<<<1, 1024, 0, stream>>>(btot, bbase, he_ptr, NUM_HE, nb_he, E);
    fill_csr<5><<<nb_he, 256, 0, stream>>>(
        staging, counts, boffs, bbase, he_ptr, he_mem, NUM_HE, nb_he, nblk);

    // Stage 2: hyperedge aggregation (uses he CSR; staging then free for nd)
    gather_he<<<(NUM_HE + 3) / 4, 256, 0, stream>>>(
        (const uint2*)Kbuf, he_ptr, he_mem, (uint2*)he_feat, NUM_HE);

    // CSR by node (SHIFT=7), reusing counts/boffs/btot/bbase/staging
    stage_pairs<7, 800><<<nblk, 256, 0, stream>>>(
        node_idx, he_idx, counts, boffs, staging, E, nb_nd);
    bucket_tot<<<(nb_nd + 3) / 4, 256, 0, stream>>>(counts, btot, nb_nd, nblk);
    bucket_scan<<<1, 1024, 0, stream>>>(btot, bbase, nd_ptr, N, nb_nd, E);
    fill_csr<7><<<nb_nd, 256, 0, stream>>>(
        staging, counts, boffs, bbase, nd_ptr, nd_he, N, nb_nd, nblk);

    // Stages 3-5: fused attention (bf16 K dead; Kbuf region becomes bf16 node_out)
    fused_attn<<<(N + 3) / 4, 256, 0, stream>>>(
        Qbuf, (const uint2*)he_feat, nd_ptr, nd_he, (uint2*)Kbuf, N);

    // Stage 6: residual (x fp32) + bf16 node_out @ Wa
    gemm_out<<<gemm_grid, 256, 0, stream>>>(
        (const unsigned short*)Kbuf, x, wfrag + 65536, wfrag + 81920, ba, out, N);
}